// Round 8
// baseline (3131.025 us; speedup 1.0000x reference)
//
#include <hip/hip_runtime.h>
#include <hip/hip_bf16.h>

// Decoder: T=50, B=64, S=400, D=E=H=A=512, POOL=2.
// R8: ONE kernel per scan step (grid 264 = 8 GRU blocks + 256 energy blocks),
// intra-step GRU->energy handoff via agent-scope qpart + vmcnt(0)+flag (R6-validated
// mechanism, small payload only). Energy blocks finalize step t-1 chunk-locally
// while GRU runs. Max-free softmax (R7). 59 dispatch slots total.

#define T_STEPS 50
#define BB 64
#define SS 400

// output offsets (floats)
#define O_GOUT 0
#define O_HID 819200
#define O_ATTN_LAST 851968
#define O_CTXF 877568
#define O_PG 910336
#define O_GATTN 913536
#define O_COVL 2193536
#define O_COVF 2196736

typedef __attribute__((ext_vector_type(4))) float f4;
typedef __attribute__((ext_vector_type(8))) short s8v;
typedef __attribute__((ext_vector_type(4))) unsigned u4;

static __device__ __forceinline__ float bf2f(unsigned short u){
  unsigned v = ((unsigned)u) << 16; return __builtin_bit_cast(float, v);
}
static __device__ __forceinline__ unsigned short f2bf(float f){
  unsigned u = __builtin_bit_cast(unsigned, f);
  unsigned r = (u + 0x7FFFu + ((u >> 16) & 1u)) >> 16;
  return (unsigned short)r;
}
static __device__ __forceinline__ float sigmoidf_(float x){ return 1.f/(1.f+__expf(-x)); }
static __device__ __forceinline__ float tanhf_(float x){ float e=__expf(2.f*x); return 1.f - 2.f/(e+1.f); }
static __device__ __forceinline__ float ald32f(const float* p){
  unsigned u = __hip_atomic_load((const unsigned*)p, __ATOMIC_RELAXED, __HIP_MEMORY_SCOPE_AGENT);
  return __builtin_bit_cast(float, u);
}
static __device__ __forceinline__ void ast32f(float* p, float v){
  __hip_atomic_store((unsigned*)p, __builtin_bit_cast(unsigned, v),
                     __ATOMIC_RELAXED, __HIP_MEMORY_SCOPE_AGENT);
}

// ---------------- converts ----------------
__global__ void conv_ctx(const float* __restrict__ ctx, unsigned short* __restrict__ out){
  int o = blockIdx.x*256 + threadIdx.x;           // [S][B][E] -> [B][S][E] bf16
  if(o >= SS*BB*512) return;
  int e = o & 511; int b = (o>>9)&63; int s = o>>15;
  out[((b*SS+s)<<9) + e] = f2bf(ctx[o]);
}
__global__ void conv_emb(const int* __restrict__ y, const float* __restrict__ embW,
                         unsigned short* __restrict__ embU){
  int o = blockIdx.x*256+threadIdx.x; if(o>=T_STEPS*BB*512) return;
  int d = o & 511; int i = o>>9;
  embU[o] = f2bf(embW[(long)y[i]*512 + d]);
}
// fused small converts + init (+flag zeroing)
__global__ void conv_rest(const float* __restrict__ W_ih, const float* __restrict__ W_hh,
                          const float* __restrict__ W_pre, const float* __restrict__ W_ro,
                          const float* __restrict__ W_q,
                          const float* __restrict__ hidden, const float* __restrict__ init_att,
                          const float* __restrict__ gctx, const float* __restrict__ coverage,
                          unsigned short* __restrict__ wihbf, unsigned short* __restrict__ wpreT,
                          unsigned short* __restrict__ wroT, unsigned short* __restrict__ Wgru,
                          unsigned short* __restrict__ WqP,
                          float* __restrict__ hrow0, unsigned short* __restrict__ h0bf_init,
                          unsigned short* __restrict__ ctx0bf, float* __restrict__ gctxT,
                          float* __restrict__ cov, unsigned* __restrict__ flags){
  int o = blockIdx.x*256+threadIdx.x;
  if(o < 786432){
    int j = o>>9; int d = o&511;
    wihbf[o] = f2bf(W_ih[(long)j*1024 + d]);
  } else if(o < 1048576){
    int p = o - 786432;
    int a = p>>9; int e = p&511;
    wpreT[p] = f2bf(W_pre[(long)e*512 + a]);
  } else if(o < 2097152){
    int p = o - 1048576;
    int n = p>>11; int k = p&2047;
    wroT[p] = f2bf(W_ro[(long)k*512 + n]);
  } else if(o < 3670016){
    int p = o - 2097152;
    int rg = p >> 13; int rem = p & 8191;
    int ki = rem >> 9; int ln = (rem >> 3) & 63; int e = p & 7;
    int blk = rg/24; int r2 = rg%24; int w = r2/6; int r3 = r2%6; int g = r3>>1; int op = r3&1;
    int rl = ln & 15; int kk = ((ln>>4)<<3) + e;
    int d = blk*64 + w*16 + rl; int j = g*512 + d; int k = ki*32 + kk;
    float v = op ? W_hh[(long)j*512 + k] : W_ih[(long)j*1024 + 512 + k];
    Wgru[p] = f2bf(v);
  } else if(o < 3932160){
    int p = o - 3670016;
    int e = p&7; int ln=(p>>3)&63; int kf=(p>>9)&1; int nrg=(p>>10)&31; int blk=p>>15;
    int n = nrg*16 + (ln&15);
    int k = blk*64 + kf*32 + ((ln>>4)<<3) + e;
    WqP[p] = f2bf(W_q[(long)k*512 + n]);
  } else if(o < 4056128){
    int p = o - 3932160;
    if(p < 32768){ float v = hidden[p]; hrow0[p] = v; h0bf_init[p] = f2bf(v); }
    else if(p < 65536){ int q=p-32768; ctx0bf[q] = f2bf(init_att[q]); }
    else if(p < 98304){ int q=p-65536; int b=q>>9,e=q&511; gctxT[e*64+b]=gctx[q]; }
    else if(p < 123904){ int q=p-98304; cov[q]=coverage[q]; }
    else { int q=p-123904; if(q<64) flags[q]=0u; }
  }
}

// ---------------- MFMA GEMM (precompute) ----------------
template<int OUT_BF16>
__global__ __launch_bounds__(256) void mfma_gemm(
    const unsigned short* __restrict__ Abf, int lda,
    const unsigned short* __restrict__ Bbf, int ldb,
    void* __restrict__ Cp, int ldc, const float* __restrict__ bias, int K)
{
  __shared__ __align__(16) unsigned short Ash[128*40];
  __shared__ __align__(16) unsigned short Bsh[128*40];
  int m0 = blockIdx.x*128, n0 = blockIdx.y*128;
  int tid = threadIdx.x;
  int wid = tid>>6, lane = tid&63;
  int wm = wid>>1, wn = wid&1;
  int lr = lane&15, lg = lane>>4;
  f4 acc[4][4];
  #pragma unroll
  for(int i=0;i<4;i++)
    #pragma unroll
    for(int j=0;j<4;j++) acc[i][j]=(f4)0.f;

  for(int kt=0; kt<K; kt+=32){
    #pragma unroll
    for(int c=0;c<2;c++){
      int flat = tid*16 + c*8;
      int row = flat>>5, col = flat&31;
      const unsigned short* ga = Abf + (long)(m0+row)*lda + kt + col;
      *(uint4*)(&Ash[row*40+col]) = *(const uint4*)ga;
      const unsigned short* gb = Bbf + (long)(n0+row)*ldb + kt + col;
      *(uint4*)(&Bsh[row*40+col]) = *(const uint4*)gb;
    }
    __syncthreads();
    s8v av[4], bv[4];
    #pragma unroll
    for(int mi=0;mi<4;mi++) av[mi] = *(const s8v*)(&Ash[(wm*64+mi*16+lr)*40 + lg*8]);
    #pragma unroll
    for(int ni=0;ni<4;ni++) bv[ni] = *(const s8v*)(&Bsh[(wn*64+ni*16+lr)*40 + lg*8]);
    #pragma unroll
    for(int mi=0;mi<4;mi++)
      #pragma unroll
      for(int ni=0;ni<4;ni++)
        acc[mi][ni] = __builtin_amdgcn_mfma_f32_16x16x32_bf16(av[mi], bv[ni], acc[mi][ni], 0,0,0);
    __syncthreads();
  }
  #pragma unroll
  for(int mi=0;mi<4;mi++)
    #pragma unroll
    for(int ni=0;ni<4;ni++){
      int gc = n0 + wn*64 + ni*16 + lr;
      #pragma unroll
      for(int r=0;r<4;r++){
        int gr = m0 + wm*64 + mi*16 + lg*4 + r;
        float v = acc[mi][ni][r];
        if(bias) v += bias[gc];
        if(OUT_BF16) ((unsigned short*)Cp)[(long)gr*ldc + gc] = f2bf(v);
        else         ((float*)Cp)[(long)gr*ldc + gc] = v;
      }
    }
}

// ---------------- 3-source RO GEMM ----------------
__global__ __launch_bounds__(256) void mfma_gemm_ro(
    const unsigned short* __restrict__ embU, const unsigned short* __restrict__ h0bf,
    const unsigned short* __restrict__ ctxA, const unsigned short* __restrict__ wroT,
    float* __restrict__ RO, const float* __restrict__ bias)
{
  __shared__ __align__(16) unsigned short Ash[128*40];
  __shared__ __align__(16) unsigned short Bsh[128*40];
  int m0 = blockIdx.x*128, n0 = blockIdx.y*128;
  int tid = threadIdx.x;
  int wid = tid>>6, lane = tid&63;
  int wm = wid>>1, wn = wid&1;
  int lr = lane&15, lg = lane>>4;
  f4 acc[4][4];
  #pragma unroll
  for(int i=0;i<4;i++)
    #pragma unroll
    for(int j=0;j<4;j++) acc[i][j]=(f4)0.f;

  for(int kt=0; kt<1536; kt+=32){
    const unsigned short* src = (kt<512) ? embU : (kt<1024) ? h0bf : ctxA;
    int klocal = kt & 511;
    #pragma unroll
    for(int c=0;c<2;c++){
      int flat = tid*16 + c*8;
      int row = flat>>5, col = flat&31;
      *(uint4*)(&Ash[row*40+col]) = *(const uint4*)(src + (long)(m0+row)*512 + klocal + col);
      *(uint4*)(&Bsh[row*40+col]) = *(const uint4*)(wroT + (long)(n0+row)*2048 + kt + col);
    }
    __syncthreads();
    s8v av[4], bv[4];
    #pragma unroll
    for(int mi=0;mi<4;mi++) av[mi] = *(const s8v*)(&Ash[(wm*64+mi*16+lr)*40 + lg*8]);
    #pragma unroll
    for(int ni=0;ni<4;ni++) bv[ni] = *(const s8v*)(&Bsh[(wn*64+ni*16+lr)*40 + lg*8]);
    #pragma unroll
    for(int mi=0;mi<4;mi++)
      #pragma unroll
      for(int ni=0;ni<4;ni++)
        acc[mi][ni] = __builtin_amdgcn_mfma_f32_16x16x32_bf16(av[mi], bv[ni], acc[mi][ni], 0,0,0);
    __syncthreads();
  }
  #pragma unroll
  for(int mi=0;mi<4;mi++)
    #pragma unroll
    for(int ni=0;ni<4;ni++){
      int gc = n0 + wn*64 + ni*16 + lr;
      #pragma unroll
      for(int r=0;r<4;r++){
        int gr = m0 + wm*64 + mi*16 + lg*4 + r;
        RO[(long)gr*512 + gc] = acc[mi][ni][r] + bias[gc];
      }
    }
}

// ---------------- fused small fp32 GEMMs: q_g and ro_g ----------------
__global__ __launch_bounds__(256) void small2(
  const float* __restrict__ AT, const float* __restrict__ W_q, const float* __restrict__ W_ro,
  float* __restrict__ q_g, float* __restrict__ ro_g)
{
  int blk = blockIdx.x;
  int half = blk>>7; int nblk = blk&127;
  int tid = threadIdx.x;
  int b = tid&63; int nq = tid>>6;
  int n = __builtin_amdgcn_readfirstlane(nblk*4 + nq);
  const float* W = half ? W_ro : W_q;
  int koff = half ? 1536 : 512;
  float acc = 0.f;
  const float* wp = W + (long)koff*512 + n;
  #pragma unroll 8
  for(int k=0;k<512;k++){
    acc = fmaf(AT[k*64+b], wp[(long)k*512], acc);
  }
  (half ? ro_g : q_g)[b*512+n] = acc;
}

// ---------------- fused per-step kernel ----------------
// blocks 0..7: GRU(t) + q-partials -> agent qpart, vmcnt(0), flags[t]+=1
// blocks 8..263: finalize(t-1) chunk-local -> wait flags[t]==8 -> q reduce ->
//                energy+exp -> S_part/P_exp -> ctx partials -> ctxP
__global__ __launch_bounds__(512) void k_step(
  const unsigned short* __restrict__ ctx0bf, float* __restrict__ ctxP,
  float* __restrict__ S_part, float* __restrict__ P_exp,
  const unsigned short* __restrict__ hprevbf,
  const float* __restrict__ hrow_in, float* __restrict__ hrow_out,
  const unsigned short* __restrict__ Wp, const unsigned short* __restrict__ WqP,
  const float* __restrict__ gi_emb, const float* __restrict__ b_hh,
  unsigned short* __restrict__ h0bf_all, float* __restrict__ qpart,
  float* __restrict__ cov, unsigned short* __restrict__ ctxA,
  const unsigned short* __restrict__ pre, const unsigned short* __restrict__ ctxbf,
  const float* __restrict__ q_g, const float* __restrict__ Wv,
  const float* __restrict__ Wcov, const float* __restrict__ padm,
  float* __restrict__ covl_part, unsigned* __restrict__ flags,
  float* __restrict__ outp, int t)
{
  __shared__ __align__(16) char smem[75008];
  const int blk = blockIdx.x;
  const int tid = threadIdx.x;
  const int w = tid>>6, lane = tid&63;
  const int lr = lane&15, lg = lane>>4;

  if(blk < 8){
    // ================= GRU block =================
    unsigned short* Ash = (unsigned short*)smem;            // 64KB
    unsigned short* HS  = (unsigned short*)(smem+65536);    // 9.2KB
    float* invS = (float*)(smem+74752);                     // 64 floats
    const int swz = (lr&7)<<4;
    const int rgbase = blk*24 + w*6;                        // valid for w<4

    if(t>0 && tid<64){
      const float* Sp = S_part + ((t-1)&1)*256 + tid*4;
      invS[tid] = 1.f/(Sp[0]+Sp[1]+Sp[2]+Sp[3]);
    }
    __syncthreads();

    f4 acc2[6][4];
    #pragma unroll
    for(int u=0;u<6;u++)
      #pragma unroll
      for(int mi=0;mi<4;mi++) acc2[u][mi]=(f4)0.f;

    for(int kp=0; kp<2; kp++){
      for(int c = tid; c < 4096; c += 512){
        int op = c>>11; int row = (c>>5)&63; int kc = c&31;
        int e0 = kp*256 + kc*8;
        u4 v;
        if(op){
          v = *(const u4*)(hprevbf + row*512 + e0);
        } else if(t>0){
          const float* cp = ctxP + (long)row*2048 + e0;
          float sc = invS[row];
          f4 a0 = *(const f4*)(cp);
          f4 a1 = *(const f4*)(cp+512);
          f4 a2 = *(const f4*)(cp+1024);
          f4 a3 = *(const f4*)(cp+1536);
          f4 b0 = *(const f4*)(cp+4);
          f4 b1 = *(const f4*)(cp+516);
          f4 b2 = *(const f4*)(cp+1028);
          f4 b3 = *(const f4*)(cp+1540);
          f4 s0 = (a0+a1+a2+a3)*sc;
          f4 s1 = (b0+b1+b2+b3)*sc;
          v.x = (unsigned)f2bf(s0.x) | ((unsigned)f2bf(s0.y)<<16);
          v.y = (unsigned)f2bf(s0.z) | ((unsigned)f2bf(s0.w)<<16);
          v.z = (unsigned)f2bf(s1.x) | ((unsigned)f2bf(s1.y)<<16);
          v.w = (unsigned)f2bf(s1.z) | ((unsigned)f2bf(s1.w)<<16);
          if(blk == (row>>3))
            *(u4*)(ctxA + ((long)((t-1)*64+row))*512 + e0) = v;
        } else {
          v = *(const u4*)(ctx0bf + row*512 + e0);
        }
        int dst = op*32768 + row*512 + ((kc*16) ^ ((row&7)<<4));
        *(u4*)((char*)Ash + dst) = v;
      }
      __syncthreads();
      if(w<4){
        #pragma unroll 2
        for(int ktl=0; ktl<256; ktl+=32){
          s8v av[2][4];
          #pragma unroll
          for(int op=0;op<2;op++)
            #pragma unroll
            for(int mi=0;mi<4;mi++)
              av[op][mi] = *(const s8v*)((const char*)Ash + op*32768 + (mi*16+lr)*512 + ((ktl*2 + lg*16) ^ swz));
          int ki = kp*8 + (ktl>>5);
          const unsigned short* wb = Wp + (long)rgbase*8192 + ki*512 + lane*8;
          #pragma unroll
          for(int u=0;u<6;u++){
            s8v bv = *(const s8v*)(wb + (long)u*8192);
            #pragma unroll
            for(int mi=0;mi<4;mi++)
              acc2[u][mi] = __builtin_amdgcn_mfma_f32_16x16x32_bf16(av[u&1][mi], bv, acc2[u][mi], 0,0,0);
          }
        }
      }
      __syncthreads();
    }

    if(w<4){
      int d = blk*64 + w*16 + lr;
      float bhr = b_hh[d], bhz = b_hh[512+d], bhn = b_hh[1024+d];
      #pragma unroll
      for(int mi=0;mi<4;mi++){
        #pragma unroll
        for(int r=0;r<4;r++){
          int b = mi*16 + lg*4 + r;
          const float* ge = gi_emb + (long)(t*64+b)*1536;
          float g0 = __builtin_nontemporal_load(ge + d);
          float g1 = __builtin_nontemporal_load(ge + 512 + d);
          float g2 = __builtin_nontemporal_load(ge + 1024 + d);
          float rr = sigmoidf_(g0 + bhr + acc2[0][mi][r] + acc2[1][mi][r]);
          float zz = sigmoidf_(g1 + bhz + acc2[2][mi][r] + acc2[3][mi][r]);
          float nn = tanhf_(  g2       + acc2[4][mi][r] + rr*(acc2[5][mi][r] + bhn));
          float hp = hrow_in[b*512 + d];
          float hv = (1.f-zz)*nn + zz*hp;
          hrow_out[b*512+d] = hv;
          unsigned short hb = f2bf(hv);
          h0bf_all[(long)(t*64+b)*512 + d] = hb;
          HS[b*72 + w*16 + lr] = hb;
          if(t==T_STEPS-1) outp[O_HID + b*512 + d] = hv;
        }
      }
    }
    __syncthreads();
    // q-partials (agent-scope stores)
    if(w<4){
      #pragma unroll
      for(int i=0;i<8;i++){
        f4 accq[4];
        #pragma unroll
        for(int mi=0;mi<4;mi++) accq[mi]=(f4)0.f;
        #pragma unroll
        for(int kf=0;kf<2;kf++){
          s8v bv = *(const s8v*)(WqP + ((((long)blk*32 + (w*8+i))*2 + kf)*64 + lane)*8);
          #pragma unroll
          for(int mi=0;mi<4;mi++){
            s8v av = *(const s8v*)(HS + (mi*16+lr)*72 + kf*32 + lg*8);
            accq[mi] = __builtin_amdgcn_mfma_f32_16x16x32_bf16(av, bv, accq[mi], 0,0,0);
          }
        }
        int n = w*128 + i*16 + lr;
        #pragma unroll
        for(int mi=0;mi<4;mi++)
          #pragma unroll
          for(int r=0;r<4;r++)
            ast32f(qpart + (long)blk*32768 + (long)(mi*16+lg*4+r)*512 + n, accq[mi][r]);
      }
    }
    asm volatile("s_waitcnt vmcnt(0)" ::: "memory");
    __syncthreads();
    if(tid==0)
      __hip_atomic_fetch_add(flags+t, 1u, __ATOMIC_RELEASE, __HIP_MEMORY_SCOPE_AGENT);
    return;
  }

  // ================= energy block =================
  {
    int eb = blk-8; int b = eb>>2, cq = eb&3, c0 = cq*100;
    float* q_sh  = (float*)smem;
    float* wv_sh = (float*)(smem+2048);
    float* wc_sh = (float*)(smem+4096);
    float* covL  = (float*)(smem+6144);
    float* padL  = (float*)(smem+6560);
    float* pL    = (float*)(smem+6976);
    float* red   = (float*)(smem+7392);
    float* red2  = (float*)(smem+9440);
    float* pb    = (float*)(smem+9472);   // [8][512]

    wv_sh[tid]=Wv[tid]; wc_sh[tid]=Wcov[tid];
    if(tid<100) padL[tid]=padm[b*400+c0+tid];
    // finalize step t-1 for this chunk (overlaps GRU)
    float clp = 0.f;
    if(t>0){
      const float* Sp = S_part + ((t-1)&1)*256 + b*4;
      float inv = 1.f/(Sp[0]+Sp[1]+Sp[2]+Sp[3]);
      if(tid<100){
        float p = P_exp[b*400+c0+tid]*inv;
        float co = cov[b*400+c0+tid];
        clp = fminf(p,co);
        float nc = co+p;
        cov[b*400+c0+tid]=nc;
        covL[tid]=nc;
        outp[O_GATTN + (long)(t-1)*25600 + b*400 + c0 + tid] = p;
      }
    } else {
      if(tid<100) covL[tid]=cov[b*400+c0+tid];
    }
    red[tid]=clp; __syncthreads();
    for(int o=256;o;o>>=1){ if(tid<o) red[tid]+=red[tid+o]; __syncthreads(); }
    if(t>0 && tid==0) covl_part[(long)(t-1)*256 + b*4+cq] = red[0];
    // wait for q-partials
    if(tid==0){
      unsigned it=0;
      while(__hip_atomic_load(flags+t, __ATOMIC_RELAXED, __HIP_MEMORY_SCOPE_AGENT) < 8u){
        __builtin_amdgcn_s_sleep(8);
        if(++it > 200000000u) break;
      }
    }
    __syncthreads();
    asm volatile("" ::: "memory");
    // q reduce (agent loads)
    {
      float acc = q_g[b*512+tid];
      #pragma unroll
      for(int p=0;p<8;p++) acc += ald32f(qpart + ((long)p<<15) + b*512 + tid);
      q_sh[tid] = acc;
    }
    __syncthreads();
    // energy + exp (wave-per-row, regular cached loads)
    float wsum = 0.f;
    for(int i=w; i<100; i+=8){
      uint4 cur = *(const uint4*)(pre + (((long)(b*400+c0+i))<<9) + lane*8);
      float cv = covL[i];
      float part = 0.f;
      const unsigned* uu = (const unsigned*)&cur;
      #pragma unroll
      for(int q4=0;q4<4;q4++){
        int a = lane*8 + q4*2;
        part += wv_sh[a]  * tanhf_(bf2f((unsigned short)(uu[q4]&0xffffu)) + q_sh[a]   + cv*wc_sh[a]);
        part += wv_sh[a+1]* tanhf_(bf2f((unsigned short)(uu[q4]>>16))    + q_sh[a+1] + cv*wc_sh[a+1]);
      }
      #pragma unroll
      for(int off=32;off;off>>=1) part += __shfl_xor(part, off, 64);
      if(lane==0){
        float e = (padL[i]>0.5f) ? -1e18f : part;
        float p = __expf(e);
        pL[i] = p;
        P_exp[b*400+c0+i] = p;
        wsum += p;
      }
    }
    if(lane==0) red2[w]=wsum;
    __syncthreads();
    if(tid==0)
      S_part[(t&1)*256 + b*4+cq] = red2[0]+red2[1]+red2[2]+red2[3]+red2[4]+red2[5]+red2[6]+red2[7];
    // context partials (unnormalized)
    float acc8[8];
    #pragma unroll
    for(int j=0;j<8;j++) acc8[j]=0.f;
    for(int i=w; i<100; i+=8){
      uint4 cur = *(const uint4*)(ctxbf + (((long)(b*400+c0+i))<<9) + lane*8);
      float pv = pL[i];
      const unsigned* uu = (const unsigned*)&cur;
      acc8[0] = fmaf(pv, bf2f((unsigned short)(uu[0]&0xffffu)), acc8[0]);
      acc8[1] = fmaf(pv, bf2f((unsigned short)(uu[0]>>16)),     acc8[1]);
      acc8[2] = fmaf(pv, bf2f((unsigned short)(uu[1]&0xffffu)), acc8[2]);
      acc8[3] = fmaf(pv, bf2f((unsigned short)(uu[1]>>16)),     acc8[3]);
      acc8[4] = fmaf(pv, bf2f((unsigned short)(uu[2]&0xffffu)), acc8[4]);
      acc8[5] = fmaf(pv, bf2f((unsigned short)(uu[2]>>16)),     acc8[5]);
      acc8[6] = fmaf(pv, bf2f((unsigned short)(uu[3]&0xffffu)), acc8[6]);
      acc8[7] = fmaf(pv, bf2f((unsigned short)(uu[3]>>16)),     acc8[7]);
    }
    #pragma unroll
    for(int j=0;j<8;j++) pb[w*512 + lane*8+j] = acc8[j];
    __syncthreads();
    {
      float v = pb[tid]+pb[512+tid]+pb[1024+tid]+pb[1536+tid]
               +pb[2048+tid]+pb[2560+tid]+pb[3072+tid]+pb[3584+tid];
      ctxP[((long)b*4+cq)*512 + tid] = v;
    }
  }
}

// ---------------- k_fin: finalize step 49 + all covl ----------------
__global__ __launch_bounds__(256) void k_fin(
  const float* __restrict__ ctxP, const float* __restrict__ S_part,
  const float* __restrict__ P_exp, const float* __restrict__ cov,
  const float* __restrict__ covl_part,
  unsigned short* __restrict__ ctxA, float* __restrict__ outp)
{
  __shared__ float red[256];
  int b = blockIdx.x; int tid = threadIdx.x;
  const int tb = T_STEPS-1;
  const float* Sp = S_part + 256 + b*4;   // parity of t=49 is 1
  float S = Sp[0]+Sp[1]+Sp[2]+Sp[3];
  float inv = 1.f/S;
  float clp;
  {
    float p = P_exp[b*400+tid]*inv;
    float co = cov[b*400+tid];
    clp = fminf(p, co);
    float nc = co+p;
    outp[O_GATTN + (long)tb*25600 + b*400 + tid] = p;
    outp[O_ATTN_LAST + b*400 + tid] = p;
    outp[O_COVF + b*400 + tid] = nc;
  }
  if(tid<144){
    int i = 256+tid;
    float p = P_exp[b*400+i]*inv;
    float co = cov[b*400+i];
    clp += fminf(p, co);
    float nc = co+p;
    outp[O_GATTN + (long)tb*25600 + b*400 + i] = p;
    outp[O_ATTN_LAST + b*400 + i] = p;
    outp[O_COVF + b*400 + i] = nc;
  }
  red[tid]=clp; __syncthreads();
  for(int o=128;o;o>>=1){ if(tid<o) red[tid]+=red[tid+o]; __syncthreads(); }
  if(tid==0) outp[O_COVL + tb*64 + b] = red[0];
  if(tid<49){
    const float* cp = covl_part + (long)tid*256 + b*4;
    outp[O_COVL + tid*64 + b] = cp[0]+cp[1]+cp[2]+cp[3];
  }
  for(int c=tid;c<512;c+=256){
    float v = (ctxP[(long)b*2048+c]+ctxP[(long)b*2048+512+c]
              +ctxP[(long)b*2048+1024+c]+ctxP[(long)b*2048+1536+c])*inv;
    outp[O_CTXF + b*512 + c] = v;
    ctxA[(long)(tb*64+b)*512 + c] = f2bf(v);
  }
}

// ---------------- fused post: pgen + maxout ----------------
__global__ __launch_bounds__(256) void k_post(
  const unsigned short* __restrict__ embU, const unsigned short* __restrict__ h0bf,
  const unsigned short* __restrict__ ctxA, const float* __restrict__ Wpg,
  const float* __restrict__ bpg, const float* __restrict__ RO,
  const float* __restrict__ ro_g, float* __restrict__ outp)
{
  int blk = blockIdx.x;
  if(blk < 800){
    int wid = threadIdx.x>>6, lane=threadIdx.x&63;
    int m = blk*4 + wid;
    float acc=0.f;
    #pragma unroll
    for(int i=0;i<8;i++){
      int k = i*64+lane;
      acc = fmaf(bf2f(ctxA[(long)m*512+k]), Wpg[k], acc);
      acc = fmaf(bf2f(h0bf[(long)m*512+k]), Wpg[512+k], acc);
      acc = fmaf(bf2f(embU[(long)m*512+k]), Wpg[1024+k], acc);
    }
    #pragma unroll
    for(int off=32; off; off>>=1) acc += __shfl_xor(acc, off, 64);
    if(lane==0) outp[O_PG + m] = sigmoidf_(acc + bpg[0]);
  } else {
    int o = (blk-800)*256 + threadIdx.x;
    int h = o & 255; int m = o>>8; int b = m & 63;
    float v0 = RO[(long)m*512 + 2*h]   + ro_g[b*512 + 2*h];
    float v1 = RO[(long)m*512 + 2*h+1] + ro_g[b*512 + 2*h+1];
    outp[O_GOUT + o] = fmaxf(v0,v1);
  }
}

extern "C" void kernel_launch(void* const* d_in, const int* in_sizes, int n_in,
                              void* d_out, int out_size, void* d_ws, size_t ws_size,
                              hipStream_t stream)
{
  (void)in_sizes; (void)n_in; (void)out_size; (void)ws_size;
  const int*   y       = (const int*)d_in[0];
  const float* hidden  = (const float*)d_in[1];
  const float* context = (const float*)d_in[2];
  const float* padm    = (const float*)d_in[3];
  const float* init_att= (const float*)d_in[4];
  const float* coverage= (const float*)d_in[5];
  const float* gctx    = (const float*)d_in[6];
  const float* embW    = (const float*)d_in[7];
  const float* W_ih    = (const float*)d_in[8];
  const float* W_hh    = (const float*)d_in[9];
  const float* b_ih    = (const float*)d_in[10];
  const float* b_hh    = (const float*)d_in[11];
  const float* W_pre   = (const float*)d_in[12];
  const float* b_pre   = (const float*)d_in[13];
  const float* W_q     = (const float*)d_in[14];
  const float* W_v     = (const float*)d_in[15];
  const float* W_cov   = (const float*)d_in[16];
  const float* W_pg    = (const float*)d_in[17];
  const float* b_pg    = (const float*)d_in[18];
  const float* W_ro    = (const float*)d_in[19];
  const float* b_ro    = (const float*)d_in[20];
  float* out = (float*)d_out;

  char* wsb = (char*)d_ws;
  size_t off = 0;
  auto alloc = [&](size_t bytes)->char*{ char* p = wsb+off; off += (bytes+255)&~255UL; return p; };
  unsigned short* pre    = (unsigned short*)alloc(25600UL*512*2);
  unsigned short* ctxbf  = (unsigned short*)alloc(13107200UL*2);
  unsigned short* embU   = (unsigned short*)alloc(3200UL*512*2);
  unsigned short* wihbf  = (unsigned short*)alloc(1536UL*512*2);
  unsigned short* wpreT  = (unsigned short*)alloc(512UL*512*2);
  unsigned short* wroT   = (unsigned short*)alloc(512UL*2048*2);
  unsigned short* Wgru   = (unsigned short*)alloc(192UL*8192*2);
  unsigned short* WqP    = (unsigned short*)alloc(262144UL*2);
  float* gi_emb = (float*)alloc(3200UL*1536*4);
  float* RO     = (float*)alloc(3200UL*512*4);
  float* q_g    = (float*)alloc(64UL*512*4);
  float* ro_g   = (float*)alloc(64UL*512*4);
  float* hrow0  = (float*)alloc(64UL*512*4);
  float* hrow1  = (float*)alloc(64UL*512*4);
  float* gctxT  = (float*)alloc(512UL*64*4);
  unsigned short* h0bf = (unsigned short*)alloc(3200UL*512*2);
  unsigned short* h0bf_init = (unsigned short*)alloc(64UL*512*2);
  unsigned short* ctx0bf    = (unsigned short*)alloc(64UL*512*2);
  unsigned short* ctxA = (unsigned short*)alloc(3200UL*512*2);
  float* ctxP   = (float*)alloc(64UL*4*512*4);
  float* P_exp  = (float*)alloc(64UL*400*4);
  float* S_part = (float*)alloc(2UL*256*4);
  float* qpart  = (float*)alloc(8UL*64*512*4);
  float* cov    = (float*)alloc(64UL*400*4);
  float* covl_part = (float*)alloc(50UL*256*4);
  unsigned* flags = (unsigned*)alloc(64UL*4);

  // converts + init (3 slots)
  conv_ctx <<<dim3(51200),dim3(256),0,stream>>>(context, ctxbf);
  conv_emb <<<dim3(6400), dim3(256),0,stream>>>(y, embW, embU);
  conv_rest<<<dim3(15845),dim3(256),0,stream>>>(W_ih, W_hh, W_pre, W_ro, W_q,
                                                hidden, init_att, gctx, coverage,
                                                wihbf, wpreT, wroT, Wgru, WqP,
                                                hrow0, h0bf_init, ctx0bf, gctxT, cov, flags);

  // precompute GEMMs (3 slots)
  mfma_gemm<1><<<dim3(200,4),dim3(256),0,stream>>>(ctxbf,512, wpreT,512,  pre,   512, b_pre, 512);
  mfma_gemm<0><<<dim3(25,12),dim3(256),0,stream>>>(embU, 512, wihbf,512,  gi_emb,1536, b_ih, 512);
  small2<<<dim3(256),dim3(256),0,stream>>>(gctxT, W_q, W_ro, q_g, ro_g);

  // scan: 1 kernel/step
  for(int t=0; t<T_STEPS; t++){
    float* hin  = (t&1) ? hrow1 : hrow0;
    float* hout = (t&1) ? hrow0 : hrow1;
    const unsigned short* hprevbf = t ? (h0bf + (long)(t-1)*32768) : h0bf_init;
    k_step<<<dim3(264),dim3(512),0,stream>>>(ctx0bf, ctxP, S_part, P_exp, hprevbf,
                                             hin, hout, Wgru, WqP, gi_emb, b_hh,
                                             h0bf, qpart, cov, ctxA, pre, ctxbf,
                                             q_g, W_v, W_cov, padm, covl_part,
                                             flags, out, t);
  }

  // post (3 slots)
  k_fin<<<dim3(64),dim3(256),0,stream>>>(ctxP, S_part, P_exp, cov, covl_part, ctxA, out);
  mfma_gemm_ro<<<dim3(25,4),dim3(256),0,stream>>>(embU, h0bf, ctxA, wroT, RO, b_ro);
  k_post<<<dim3(4000),dim3(256),0,stream>>>(embU, h0bf, ctxA, W_pg, b_pg, RO, ro_g, out);
}

// Round 9
// 2779.070 us; speedup vs baseline: 1.1266x; 1.1266x over previous
//
#include <hip/hip_runtime.h>
#include <hip/hip_bf16.h>

// Decoder: T=50, B=64, S=400, D=E=H=A=512, POOL=2.
// R9: R8 structure (1 fused kernel/step, flag handoff) +
//  (a) energy blocks preload ALL pre/ctx rows into registers BEFORE the spin
//      (stream latency hidden under the GRU wait), single fused row pass;
//  (b) GRU split across 8 waves (dim-group x batch-half) halving its latency.

#define T_STEPS 50
#define BB 64
#define SS 400

// output offsets (floats)
#define O_GOUT 0
#define O_HID 819200
#define O_ATTN_LAST 851968
#define O_CTXF 877568
#define O_PG 910336
#define O_GATTN 913536
#define O_COVL 2193536
#define O_COVF 2196736

typedef __attribute__((ext_vector_type(4))) float f4;
typedef __attribute__((ext_vector_type(8))) short s8v;
typedef __attribute__((ext_vector_type(4))) unsigned u4;

static __device__ __forceinline__ float bf2f(unsigned short u){
  unsigned v = ((unsigned)u) << 16; return __builtin_bit_cast(float, v);
}
static __device__ __forceinline__ unsigned short f2bf(float f){
  unsigned u = __builtin_bit_cast(unsigned, f);
  unsigned r = (u + 0x7FFFu + ((u >> 16) & 1u)) >> 16;
  return (unsigned short)r;
}
static __device__ __forceinline__ float sigmoidf_(float x){ return 1.f/(1.f+__expf(-x)); }
static __device__ __forceinline__ float tanhf_(float x){ float e=__expf(2.f*x); return 1.f - 2.f/(e+1.f); }
static __device__ __forceinline__ float ald32f(const float* p){
  unsigned u = __hip_atomic_load((const unsigned*)p, __ATOMIC_RELAXED, __HIP_MEMORY_SCOPE_AGENT);
  return __builtin_bit_cast(float, u);
}
static __device__ __forceinline__ void ast32f(float* p, float v){
  __hip_atomic_store((unsigned*)p, __builtin_bit_cast(unsigned, v),
                     __ATOMIC_RELAXED, __HIP_MEMORY_SCOPE_AGENT);
}

// ---------------- converts ----------------
__global__ void conv_ctx(const float* __restrict__ ctx, unsigned short* __restrict__ out){
  int o = blockIdx.x*256 + threadIdx.x;           // [S][B][E] -> [B][S][E] bf16
  if(o >= SS*BB*512) return;
  int e = o & 511; int b = (o>>9)&63; int s = o>>15;
  out[((b*SS+s)<<9) + e] = f2bf(ctx[o]);
}
__global__ void conv_emb(const int* __restrict__ y, const float* __restrict__ embW,
                         unsigned short* __restrict__ embU){
  int o = blockIdx.x*256+threadIdx.x; if(o>=T_STEPS*BB*512) return;
  int d = o & 511; int i = o>>9;
  embU[o] = f2bf(embW[(long)y[i]*512 + d]);
}
// fused small converts + init (+flag zeroing)
__global__ void conv_rest(const float* __restrict__ W_ih, const float* __restrict__ W_hh,
                          const float* __restrict__ W_pre, const float* __restrict__ W_ro,
                          const float* __restrict__ W_q,
                          const float* __restrict__ hidden, const float* __restrict__ init_att,
                          const float* __restrict__ gctx, const float* __restrict__ coverage,
                          unsigned short* __restrict__ wihbf, unsigned short* __restrict__ wpreT,
                          unsigned short* __restrict__ wroT, unsigned short* __restrict__ Wgru,
                          unsigned short* __restrict__ WqP,
                          float* __restrict__ hrow0, unsigned short* __restrict__ h0bf_init,
                          unsigned short* __restrict__ ctx0bf, float* __restrict__ gctxT,
                          float* __restrict__ cov, unsigned* __restrict__ flags){
  int o = blockIdx.x*256+threadIdx.x;
  if(o < 786432){
    int j = o>>9; int d = o&511;
    wihbf[o] = f2bf(W_ih[(long)j*1024 + d]);
  } else if(o < 1048576){
    int p = o - 786432;
    int a = p>>9; int e = p&511;
    wpreT[p] = f2bf(W_pre[(long)e*512 + a]);
  } else if(o < 2097152){
    int p = o - 1048576;
    int n = p>>11; int k = p&2047;
    wroT[p] = f2bf(W_ro[(long)k*512 + n]);
  } else if(o < 3670016){
    int p = o - 2097152;
    int rg = p >> 13; int rem = p & 8191;
    int ki = rem >> 9; int ln = (rem >> 3) & 63; int e = p & 7;
    int blk = rg/24; int r2 = rg%24; int w = r2/6; int r3 = r2%6; int g = r3>>1; int op = r3&1;
    int rl = ln & 15; int kk = ((ln>>4)<<3) + e;
    int d = blk*64 + w*16 + rl; int j = g*512 + d; int k = ki*32 + kk;
    float v = op ? W_hh[(long)j*512 + k] : W_ih[(long)j*1024 + 512 + k];
    Wgru[p] = f2bf(v);
  } else if(o < 3932160){
    int p = o - 3670016;
    int e = p&7; int ln=(p>>3)&63; int kf=(p>>9)&1; int nrg=(p>>10)&31; int blk=p>>15;
    int n = nrg*16 + (ln&15);
    int k = blk*64 + kf*32 + ((ln>>4)<<3) + e;
    WqP[p] = f2bf(W_q[(long)k*512 + n]);
  } else if(o < 4056128){
    int p = o - 3932160;
    if(p < 32768){ float v = hidden[p]; hrow0[p] = v; h0bf_init[p] = f2bf(v); }
    else if(p < 65536){ int q=p-32768; ctx0bf[q] = f2bf(init_att[q]); }
    else if(p < 98304){ int q=p-65536; int b=q>>9,e=q&511; gctxT[e*64+b]=gctx[q]; }
    else if(p < 123904){ int q=p-98304; cov[q]=coverage[q]; }
    else { int q=p-123904; if(q<64) flags[q]=0u; }
  }
}

// ---------------- MFMA GEMM (precompute) ----------------
template<int OUT_BF16>
__global__ __launch_bounds__(256) void mfma_gemm(
    const unsigned short* __restrict__ Abf, int lda,
    const unsigned short* __restrict__ Bbf, int ldb,
    void* __restrict__ Cp, int ldc, const float* __restrict__ bias, int K)
{
  __shared__ __align__(16) unsigned short Ash[128*40];
  __shared__ __align__(16) unsigned short Bsh[128*40];
  int m0 = blockIdx.x*128, n0 = blockIdx.y*128;
  int tid = threadIdx.x;
  int wid = tid>>6, lane = tid&63;
  int wm = wid>>1, wn = wid&1;
  int lr = lane&15, lg = lane>>4;
  f4 acc[4][4];
  #pragma unroll
  for(int i=0;i<4;i++)
    #pragma unroll
    for(int j=0;j<4;j++) acc[i][j]=(f4)0.f;

  for(int kt=0; kt<K; kt+=32){
    #pragma unroll
    for(int c=0;c<2;c++){
      int flat = tid*16 + c*8;
      int row = flat>>5, col = flat&31;
      const unsigned short* ga = Abf + (long)(m0+row)*lda + kt + col;
      *(uint4*)(&Ash[row*40+col]) = *(const uint4*)ga;
      const unsigned short* gb = Bbf + (long)(n0+row)*ldb + kt + col;
      *(uint4*)(&Bsh[row*40+col]) = *(const uint4*)gb;
    }
    __syncthreads();
    s8v av[4], bv[4];
    #pragma unroll
    for(int mi=0;mi<4;mi++) av[mi] = *(const s8v*)(&Ash[(wm*64+mi*16+lr)*40 + lg*8]);
    #pragma unroll
    for(int ni=0;ni<4;ni++) bv[ni] = *(const s8v*)(&Bsh[(wn*64+ni*16+lr)*40 + lg*8]);
    #pragma unroll
    for(int mi=0;mi<4;mi++)
      #pragma unroll
      for(int ni=0;ni<4;ni++)
        acc[mi][ni] = __builtin_amdgcn_mfma_f32_16x16x32_bf16(av[mi], bv[ni], acc[mi][ni], 0,0,0);
    __syncthreads();
  }
  #pragma unroll
  for(int mi=0;mi<4;mi++)
    #pragma unroll
    for(int ni=0;ni<4;ni++){
      int gc = n0 + wn*64 + ni*16 + lr;
      #pragma unroll
      for(int r=0;r<4;r++){
        int gr = m0 + wm*64 + mi*16 + lg*4 + r;
        float v = acc[mi][ni][r];
        if(bias) v += bias[gc];
        if(OUT_BF16) ((unsigned short*)Cp)[(long)gr*ldc + gc] = f2bf(v);
        else         ((float*)Cp)[(long)gr*ldc + gc] = v;
      }
    }
}

// ---------------- 3-source RO GEMM ----------------
__global__ __launch_bounds__(256) void mfma_gemm_ro(
    const unsigned short* __restrict__ embU, const unsigned short* __restrict__ h0bf,
    const unsigned short* __restrict__ ctxA, const unsigned short* __restrict__ wroT,
    float* __restrict__ RO, const float* __restrict__ bias)
{
  __shared__ __align__(16) unsigned short Ash[128*40];
  __shared__ __align__(16) unsigned short Bsh[128*40];
  int m0 = blockIdx.x*128, n0 = blockIdx.y*128;
  int tid = threadIdx.x;
  int wid = tid>>6, lane = tid&63;
  int wm = wid>>1, wn = wid&1;
  int lr = lane&15, lg = lane>>4;
  f4 acc[4][4];
  #pragma unroll
  for(int i=0;i<4;i++)
    #pragma unroll
    for(int j=0;j<4;j++) acc[i][j]=(f4)0.f;

  for(int kt=0; kt<1536; kt+=32){
    const unsigned short* src = (kt<512) ? embU : (kt<1024) ? h0bf : ctxA;
    int klocal = kt & 511;
    #pragma unroll
    for(int c=0;c<2;c++){
      int flat = tid*16 + c*8;
      int row = flat>>5, col = flat&31;
      *(uint4*)(&Ash[row*40+col]) = *(const uint4*)(src + (long)(m0+row)*512 + klocal + col);
      *(uint4*)(&Bsh[row*40+col]) = *(const uint4*)(wroT + (long)(n0+row)*2048 + kt + col);
    }
    __syncthreads();
    s8v av[4], bv[4];
    #pragma unroll
    for(int mi=0;mi<4;mi++) av[mi] = *(const s8v*)(&Ash[(wm*64+mi*16+lr)*40 + lg*8]);
    #pragma unroll
    for(int ni=0;ni<4;ni++) bv[ni] = *(const s8v*)(&Bsh[(wn*64+ni*16+lr)*40 + lg*8]);
    #pragma unroll
    for(int mi=0;mi<4;mi++)
      #pragma unroll
      for(int ni=0;ni<4;ni++)
        acc[mi][ni] = __builtin_amdgcn_mfma_f32_16x16x32_bf16(av[mi], bv[ni], acc[mi][ni], 0,0,0);
    __syncthreads();
  }
  #pragma unroll
  for(int mi=0;mi<4;mi++)
    #pragma unroll
    for(int ni=0;ni<4;ni++){
      int gc = n0 + wn*64 + ni*16 + lr;
      #pragma unroll
      for(int r=0;r<4;r++){
        int gr = m0 + wm*64 + mi*16 + lg*4 + r;
        RO[(long)gr*512 + gc] = acc[mi][ni][r] + bias[gc];
      }
    }
}

// ---------------- fused small fp32 GEMMs: q_g and ro_g ----------------
__global__ __launch_bounds__(256) void small2(
  const float* __restrict__ AT, const float* __restrict__ W_q, const float* __restrict__ W_ro,
  float* __restrict__ q_g, float* __restrict__ ro_g)
{
  int blk = blockIdx.x;
  int half = blk>>7; int nblk = blk&127;
  int tid = threadIdx.x;
  int b = tid&63; int nq = tid>>6;
  int n = __builtin_amdgcn_readfirstlane(nblk*4 + nq);
  const float* W = half ? W_ro : W_q;
  int koff = half ? 1536 : 512;
  float acc = 0.f;
  const float* wp = W + (long)koff*512 + n;
  #pragma unroll 8
  for(int k=0;k<512;k++){
    acc = fmaf(AT[k*64+b], wp[(long)k*512], acc);
  }
  (half ? ro_g : q_g)[b*512+n] = acc;
}

// ---------------- fused per-step kernel ----------------
__global__ __launch_bounds__(512) void k_step(
  const unsigned short* __restrict__ ctx0bf, float* __restrict__ ctxP,
  float* __restrict__ S_part, float* __restrict__ P_exp,
  const unsigned short* __restrict__ hprevbf,
  const float* __restrict__ hrow_in, float* __restrict__ hrow_out,
  const unsigned short* __restrict__ Wp, const unsigned short* __restrict__ WqP,
  const float* __restrict__ gi_emb, const float* __restrict__ b_hh,
  unsigned short* __restrict__ h0bf_all, float* __restrict__ qpart,
  float* __restrict__ cov, unsigned short* __restrict__ ctxA,
  const unsigned short* __restrict__ pre, const unsigned short* __restrict__ ctxbf,
  const float* __restrict__ q_g, const float* __restrict__ Wv,
  const float* __restrict__ Wcov, const float* __restrict__ padm,
  float* __restrict__ covl_part, unsigned* __restrict__ flags,
  float* __restrict__ outp, int t)
{
  __shared__ __align__(16) char smem[75008];
  const int blk = blockIdx.x;
  const int tid = threadIdx.x;
  const int w = tid>>6, lane = tid&63;
  const int lr = lane&15, lg = lane>>4;

  if(blk < 8){
    // ================= GRU block (8 waves: dim-group x batch-half) =================
    unsigned short* Ash = (unsigned short*)smem;            // 64KB
    unsigned short* HS  = (unsigned short*)(smem+65536);    // 9.2KB
    float* invS = (float*)(smem+74752);                     // 64 floats
    const int swz = (lr&7)<<4;
    const int dg = w&3, bh = w>>2;
    const int rgbase = blk*24 + dg*6;

    if(t>0 && tid<64){
      const float* Sp = S_part + ((t-1)&1)*256 + tid*4;
      invS[tid] = 1.f/(Sp[0]+Sp[1]+Sp[2]+Sp[3]);
    }
    __syncthreads();

    f4 acc2[6][2];
    #pragma unroll
    for(int u=0;u<6;u++)
      #pragma unroll
      for(int mm=0;mm<2;mm++) acc2[u][mm]=(f4)0.f;

    for(int kp=0; kp<2; kp++){
      for(int c = tid; c < 4096; c += 512){
        int op = c>>11; int row = (c>>5)&63; int kc = c&31;
        int e0 = kp*256 + kc*8;
        u4 v;
        if(op){
          v = *(const u4*)(hprevbf + row*512 + e0);
        } else if(t>0){
          const float* cp = ctxP + (long)row*2048 + e0;
          float sc = invS[row];
          f4 a0 = *(const f4*)(cp);
          f4 a1 = *(const f4*)(cp+512);
          f4 a2 = *(const f4*)(cp+1024);
          f4 a3 = *(const f4*)(cp+1536);
          f4 b0 = *(const f4*)(cp+4);
          f4 b1 = *(const f4*)(cp+516);
          f4 b2 = *(const f4*)(cp+1028);
          f4 b3 = *(const f4*)(cp+1540);
          f4 s0 = (a0+a1+a2+a3)*sc;
          f4 s1 = (b0+b1+b2+b3)*sc;
          v.x = (unsigned)f2bf(s0.x) | ((unsigned)f2bf(s0.y)<<16);
          v.y = (unsigned)f2bf(s0.z) | ((unsigned)f2bf(s0.w)<<16);
          v.z = (unsigned)f2bf(s1.x) | ((unsigned)f2bf(s1.y)<<16);
          v.w = (unsigned)f2bf(s1.z) | ((unsigned)f2bf(s1.w)<<16);
          if(blk == (row>>3))
            *(u4*)(ctxA + ((long)((t-1)*64+row))*512 + e0) = v;
        } else {
          v = *(const u4*)(ctx0bf + row*512 + e0);
        }
        int dst = op*32768 + row*512 + ((kc*16) ^ ((row&7)<<4));
        *(u4*)((char*)Ash + dst) = v;
      }
      __syncthreads();
      {
        #pragma unroll 2
        for(int ktl=0; ktl<256; ktl+=32){
          s8v av[2][2];
          #pragma unroll
          for(int op=0;op<2;op++)
            #pragma unroll
            for(int mm=0;mm<2;mm++){
              int mi = bh*2+mm;
              av[op][mm] = *(const s8v*)((const char*)Ash + op*32768 + (mi*16+lr)*512 + ((ktl*2 + lg*16) ^ swz));
            }
          int ki = kp*8 + (ktl>>5);
          const unsigned short* wb = Wp + (long)rgbase*8192 + ki*512 + lane*8;
          #pragma unroll
          for(int u=0;u<6;u++){
            s8v bv = *(const s8v*)(wb + (long)u*8192);
            #pragma unroll
            for(int mm=0;mm<2;mm++)
              acc2[u][mm] = __builtin_amdgcn_mfma_f32_16x16x32_bf16(av[u&1][mm], bv, acc2[u][mm], 0,0,0);
          }
        }
      }
      __syncthreads();
    }

    {
      int d = blk*64 + dg*16 + lr;
      float bhr = b_hh[d], bhz = b_hh[512+d], bhn = b_hh[1024+d];
      #pragma unroll
      for(int mm=0;mm<2;mm++){
        int mi = bh*2+mm;
        #pragma unroll
        for(int r=0;r<4;r++){
          int b = mi*16 + lg*4 + r;
          const float* ge = gi_emb + (long)(t*64+b)*1536;
          float g0 = __builtin_nontemporal_load(ge + d);
          float g1 = __builtin_nontemporal_load(ge + 512 + d);
          float g2 = __builtin_nontemporal_load(ge + 1024 + d);
          float rr = sigmoidf_(g0 + bhr + acc2[0][mm][r] + acc2[1][mm][r]);
          float zz = sigmoidf_(g1 + bhz + acc2[2][mm][r] + acc2[3][mm][r]);
          float nn = tanhf_(  g2       + acc2[4][mm][r] + rr*(acc2[5][mm][r] + bhn));
          float hp = hrow_in[b*512 + d];
          float hv = (1.f-zz)*nn + zz*hp;
          hrow_out[b*512+d] = hv;
          unsigned short hb = f2bf(hv);
          h0bf_all[(long)(t*64+b)*512 + d] = hb;
          HS[b*72 + dg*16 + lr] = hb;
          if(t==T_STEPS-1) outp[O_HID + b*512 + d] = hv;
        }
      }
    }
    __syncthreads();
    // q-partials: wave handles nrg = dg*8+i, batch-half bh
    {
      #pragma unroll
      for(int i=0;i<8;i++){
        f4 accq[2];
        accq[0]=(f4)0.f; accq[1]=(f4)0.f;
        #pragma unroll
        for(int kf=0;kf<2;kf++){
          s8v bv = *(const s8v*)(WqP + ((((long)blk*32 + (dg*8+i))*2 + kf)*64 + lane)*8);
          #pragma unroll
          for(int mm=0;mm<2;mm++){
            int mi = bh*2+mm;
            s8v av = *(const s8v*)(HS + (mi*16+lr)*72 + kf*32 + lg*8);
            accq[mm] = __builtin_amdgcn_mfma_f32_16x16x32_bf16(av, bv, accq[mm], 0,0,0);
          }
        }
        int n = dg*128 + i*16 + lr;
        #pragma unroll
        for(int mm=0;mm<2;mm++)
          #pragma unroll
          for(int r=0;r<4;r++)
            ast32f(qpart + (long)blk*32768 + (long)((bh*2+mm)*16+lg*4+r)*512 + n, accq[mm][r]);
      }
    }
    asm volatile("s_waitcnt vmcnt(0)" ::: "memory");
    __syncthreads();
    if(tid==0)
      __hip_atomic_fetch_add(flags+t, 1u, __ATOMIC_RELEASE, __HIP_MEMORY_SCOPE_AGENT);
    return;
  }

  // ================= energy block =================
  {
    int eb = blk-8; int b = eb>>2, cq = eb&3, c0 = cq*100;
    float* q_sh  = (float*)smem;
    float* wv_sh = (float*)(smem+2048);
    float* wc_sh = (float*)(smem+4096);
    float* covL  = (float*)(smem+6144);
    float* padL  = (float*)(smem+6560);
    float* red   = (float*)(smem+7392);
    float* red2  = (float*)(smem+9440);
    float* pb    = (float*)(smem+9472);   // [8][512]

    wv_sh[tid]=Wv[tid]; wc_sh[tid]=Wcov[tid];
    if(tid<100) padL[tid]=padm[b*400+c0+tid];
    // finalize step t-1 for this chunk (overlaps GRU)
    float clp = 0.f;
    if(t>0){
      const float* Sp = S_part + ((t-1)&1)*256 + b*4;
      float inv = 1.f/(Sp[0]+Sp[1]+Sp[2]+Sp[3]);
      if(tid<100){
        float p = P_exp[b*400+c0+tid]*inv;
        float co = cov[b*400+c0+tid];
        clp = fminf(p,co);
        float nc = co+p;
        cov[b*400+c0+tid]=nc;
        covL[tid]=nc;
        outp[O_GATTN + (long)(t-1)*25600 + b*400 + c0 + tid] = p;
      }
    } else {
      if(tid<100) covL[tid]=cov[b*400+c0+tid];
    }
    // preload this block's entire pre+ctx streams into registers (flies during GRU wait)
    const unsigned short* prow = pre   + (((long)(b*400+c0))<<9) + lane*8;
    const unsigned short* crow = ctxbf + (((long)(b*400+c0))<<9) + lane*8;
    u4 pr[13], cr[13];
    #pragma unroll
    for(int j=0;j<13;j++){
      int i = w + j*8;
      long ro = (long)((i<100)? i : 0) << 9;
      pr[j] = *(const u4*)(prow + ro);
      cr[j] = *(const u4*)(crow + ro);
    }
    red[tid]=clp; __syncthreads();
    for(int o=256;o;o>>=1){ if(tid<o) red[tid]+=red[tid+o]; __syncthreads(); }
    if(t>0 && tid==0) covl_part[(long)(t-1)*256 + b*4+cq] = red[0];
    // wait for q-partials
    if(tid==0){
      unsigned it=0;
      while(__hip_atomic_load(flags+t, __ATOMIC_RELAXED, __HIP_MEMORY_SCOPE_AGENT) < 8u){
        __builtin_amdgcn_s_sleep(8);
        if(++it > 200000000u) break;
      }
    }
    __syncthreads();
    asm volatile("" ::: "memory");
    // q reduce (agent loads)
    {
      float acc = q_g[b*512+tid];
      #pragma unroll
      for(int p=0;p<8;p++) acc += ald32f(qpart + ((long)p<<15) + b*512 + tid);
      q_sh[tid] = acc;
    }
    __syncthreads();
    // fused pass: energy -> exp -> ctx partial (registers already loaded)
    float wsum = 0.f;
    float acc8[8];
    #pragma unroll
    for(int j=0;j<8;j++) acc8[j]=0.f;
    #pragma unroll
    for(int j=0;j<13;j++){
      int i = w + j*8;
      if(i<100){
        u4 cur = pr[j];
        const unsigned* uu = (const unsigned*)&cur;
        float cv = covL[i];
        float part = 0.f;
        #pragma unroll
        for(int q4=0;q4<4;q4++){
          int a = lane*8 + q4*2;
          part += wv_sh[a]  * tanhf_(bf2f((unsigned short)(uu[q4]&0xffffu)) + q_sh[a]   + cv*wc_sh[a]);
          part += wv_sh[a+1]* tanhf_(bf2f((unsigned short)(uu[q4]>>16))    + q_sh[a+1] + cv*wc_sh[a+1]);
        }
        #pragma unroll
        for(int off=32;off;off>>=1) part += __shfl_xor(part, off, 64);
        float e = (padL[i]>0.5f) ? -1e18f : part;
        float p = __expf(e);
        if(lane==0) P_exp[b*400+c0+i] = p;
        wsum += p;
        u4 cc = cr[j];
        const unsigned* cu = (const unsigned*)&cc;
        acc8[0] = fmaf(p, bf2f((unsigned short)(cu[0]&0xffffu)), acc8[0]);
        acc8[1] = fmaf(p, bf2f((unsigned short)(cu[0]>>16)),     acc8[1]);
        acc8[2] = fmaf(p, bf2f((unsigned short)(cu[1]&0xffffu)), acc8[2]);
        acc8[3] = fmaf(p, bf2f((unsigned short)(cu[1]>>16)),     acc8[3]);
        acc8[4] = fmaf(p, bf2f((unsigned short)(cu[2]&0xffffu)), acc8[4]);
        acc8[5] = fmaf(p, bf2f((unsigned short)(cu[2]>>16)),     acc8[5]);
        acc8[6] = fmaf(p, bf2f((unsigned short)(cu[3]&0xffffu)), acc8[6]);
        acc8[7] = fmaf(p, bf2f((unsigned short)(cu[3]>>16)),     acc8[7]);
      }
    }
    if(lane==0) red2[w]=wsum;
    __syncthreads();
    if(tid==0)
      S_part[(t&1)*256 + b*4+cq] = red2[0]+red2[1]+red2[2]+red2[3]+red2[4]+red2[5]+red2[6]+red2[7];
    #pragma unroll
    for(int j=0;j<8;j++) pb[w*512 + lane*8+j] = acc8[j];
    __syncthreads();
    {
      float v = pb[tid]+pb[512+tid]+pb[1024+tid]+pb[1536+tid]
               +pb[2048+tid]+pb[2560+tid]+pb[3072+tid]+pb[3584+tid];
      ctxP[((long)b*4+cq)*512 + tid] = v;
    }
  }
}

// ---------------- k_fin: finalize step 49 + all covl ----------------
__global__ __launch_bounds__(256) void k_fin(
  const float* __restrict__ ctxP, const float* __restrict__ S_part,
  const float* __restrict__ P_exp, const float* __restrict__ cov,
  const float* __restrict__ covl_part,
  unsigned short* __restrict__ ctxA, float* __restrict__ outp)
{
  __shared__ float red[256];
  int b = blockIdx.x; int tid = threadIdx.x;
  const int tb = T_STEPS-1;
  const float* Sp = S_part + 256 + b*4;   // parity of t=49 is 1
  float S = Sp[0]+Sp[1]+Sp[2]+Sp[3];
  float inv = 1.f/S;
  float clp;
  {
    float p = P_exp[b*400+tid]*inv;
    float co = cov[b*400+tid];
    clp = fminf(p, co);
    float nc = co+p;
    outp[O_GATTN + (long)tb*25600 + b*400 + tid] = p;
    outp[O_ATTN_LAST + b*400 + tid] = p;
    outp[O_COVF + b*400 + tid] = nc;
  }
  if(tid<144){
    int i = 256+tid;
    float p = P_exp[b*400+i]*inv;
    float co = cov[b*400+i];
    clp += fminf(p, co);
    float nc = co+p;
    outp[O_GATTN + (long)tb*25600 + b*400 + i] = p;
    outp[O_ATTN_LAST + b*400 + i] = p;
    outp[O_COVF + b*400 + i] = nc;
  }
  red[tid]=clp; __syncthreads();
  for(int o=128;o;o>>=1){ if(tid<o) red[tid]+=red[tid+o]; __syncthreads(); }
  if(tid==0) outp[O_COVL + tb*64 + b] = red[0];
  if(tid<49){
    const float* cp = covl_part + (long)tid*256 + b*4;
    outp[O_COVL + tid*64 + b] = cp[0]+cp[1]+cp[2]+cp[3];
  }
  for(int c=tid;c<512;c+=256){
    float v = (ctxP[(long)b*2048+c]+ctxP[(long)b*2048+512+c]
              +ctxP[(long)b*2048+1024+c]+ctxP[(long)b*2048+1536+c])*inv;
    outp[O_CTXF + b*512 + c] = v;
    ctxA[(long)(tb*64+b)*512 + c] = f2bf(v);
  }
}

// ---------------- fused post: pgen + maxout ----------------
__global__ __launch_bounds__(256) void k_post(
  const unsigned short* __restrict__ embU, const unsigned short* __restrict__ h0bf,
  const unsigned short* __restrict__ ctxA, const float* __restrict__ Wpg,
  const float* __restrict__ bpg, const float* __restrict__ RO,
  const float* __restrict__ ro_g, float* __restrict__ outp)
{
  int blk = blockIdx.x;
  if(blk < 800){
    int wid = threadIdx.x>>6, lane=threadIdx.x&63;
    int m = blk*4 + wid;
    float acc=0.f;
    #pragma unroll
    for(int i=0;i<8;i++){
      int k = i*64+lane;
      acc = fmaf(bf2f(ctxA[(long)m*512+k]), Wpg[k], acc);
      acc = fmaf(bf2f(h0bf[(long)m*512+k]), Wpg[512+k], acc);
      acc = fmaf(bf2f(embU[(long)m*512+k]), Wpg[1024+k], acc);
    }
    #pragma unroll
    for(int off=32; off; off>>=1) acc += __shfl_xor(acc, off, 64);
    if(lane==0) outp[O_PG + m] = sigmoidf_(acc + bpg[0]);
  } else {
    int o = (blk-800)*256 + threadIdx.x;
    int h = o & 255; int m = o>>8; int b = m & 63;
    float v0 = RO[(long)m*512 + 2*h]   + ro_g[b*512 + 2*h];
    float v1 = RO[(long)m*512 + 2*h+1] + ro_g[b*512 + 2*h+1];
    outp[O_GOUT + o] = fmaxf(v0,v1);
  }
}

extern "C" void kernel_launch(void* const* d_in, const int* in_sizes, int n_in,
                              void* d_out, int out_size, void* d_ws, size_t ws_size,
                              hipStream_t stream)
{
  (void)in_sizes; (void)n_in; (void)out_size; (void)ws_size;
  const int*   y       = (const int*)d_in[0];
  const float* hidden  = (const float*)d_in[1];
  const float* context = (const float*)d_in[2];
  const float* padm    = (const float*)d_in[3];
  const float* init_att= (const float*)d_in[4];
  const float* coverage= (const float*)d_in[5];
  const float* gctx    = (const float*)d_in[6];
  const float* embW    = (const float*)d_in[7];
  const float* W_ih    = (const float*)d_in[8];
  const float* W_hh    = (const float*)d_in[9];
  const float* b_ih    = (const float*)d_in[10];
  const float* b_hh    = (const float*)d_in[11];
  const float* W_pre   = (const float*)d_in[12];
  const float* b_pre   = (const float*)d_in[13];
  const float* W_q     = (const float*)d_in[14];
  const float* W_v     = (const float*)d_in[15];
  const float* W_cov   = (const float*)d_in[16];
  const float* W_pg    = (const float*)d_in[17];
  const float* b_pg    = (const float*)d_in[18];
  const float* W_ro    = (const float*)d_in[19];
  const float* b_ro    = (const float*)d_in[20];
  float* out = (float*)d_out;

  char* wsb = (char*)d_ws;
  size_t off = 0;
  auto alloc = [&](size_t bytes)->char*{ char* p = wsb+off; off += (bytes+255)&~255UL; return p; };
  unsigned short* pre    = (unsigned short*)alloc(25600UL*512*2);
  unsigned short* ctxbf  = (unsigned short*)alloc(13107200UL*2);
  unsigned short* embU   = (unsigned short*)alloc(3200UL*512*2);
  unsigned short* wihbf  = (unsigned short*)alloc(1536UL*512*2);
  unsigned short* wpreT  = (unsigned short*)alloc(512UL*512*2);
  unsigned short* wroT   = (unsigned short*)alloc(512UL*2048*2);
  unsigned short* Wgru   = (unsigned short*)alloc(192UL*8192*2);
  unsigned short* WqP    = (unsigned short*)alloc(262144UL*2);
  float* gi_emb = (float*)alloc(3200UL*1536*4);
  float* RO     = (float*)alloc(3200UL*512*4);
  float* q_g    = (float*)alloc(64UL*512*4);
  float* ro_g   = (float*)alloc(64UL*512*4);
  float* hrow0  = (float*)alloc(64UL*512*4);
  float* hrow1  = (float*)alloc(64UL*512*4);
  float* gctxT  = (float*)alloc(512UL*64*4);
  unsigned short* h0bf = (unsigned short*)alloc(3200UL*512*2);
  unsigned short* h0bf_init = (unsigned short*)alloc(64UL*512*2);
  unsigned short* ctx0bf    = (unsigned short*)alloc(64UL*512*2);
  unsigned short* ctxA = (unsigned short*)alloc(3200UL*512*2);
  float* ctxP   = (float*)alloc(64UL*4*512*4);
  float* P_exp  = (float*)alloc(64UL*400*4);
  float* S_part = (float*)alloc(2UL*256*4);
  float* qpart  = (float*)alloc(8UL*64*512*4);
  float* cov    = (float*)alloc(64UL*400*4);
  float* covl_part = (float*)alloc(50UL*256*4);
  unsigned* flags = (unsigned*)alloc(64UL*4);

  // converts + init (3 slots)
  conv_ctx <<<dim3(51200),dim3(256),0,stream>>>(context, ctxbf);
  conv_emb <<<dim3(6400), dim3(256),0,stream>>>(y, embW, embU);
  conv_rest<<<dim3(15845),dim3(256),0,stream>>>(W_ih, W_hh, W_pre, W_ro, W_q,
                                                hidden, init_att, gctx, coverage,
                                                wihbf, wpreT, wroT, Wgru, WqP,
                                                hrow0, h0bf_init, ctx0bf, gctxT, cov, flags);

  // precompute GEMMs (3 slots)
  mfma_gemm<1><<<dim3(200,4),dim3(256),0,stream>>>(ctxbf,512, wpreT,512,  pre,   512, b_pre, 512);
  mfma_gemm<0><<<dim3(25,12),dim3(256),0,stream>>>(embU, 512, wihbf,512,  gi_emb,1536, b_ih, 512);
  small2<<<dim3(256),dim3(256),0,stream>>>(gctxT, W_q, W_ro, q_g, ro_g);

  // scan: 1 kernel/step
  for(int t=0; t<T_STEPS; t++){
    float* hin  = (t&1) ? hrow1 : hrow0;
    float* hout = (t&1) ? hrow0 : hrow1;
    const unsigned short* hprevbf = t ? (h0bf + (long)(t-1)*32768) : h0bf_init;
    k_step<<<dim3(264),dim3(512),0,stream>>>(ctx0bf, ctxP, S_part, P_exp, hprevbf,
                                             hin, hout, Wgru, WqP, gi_emb, b_hh,
                                             h0bf, qpart, cov, ctxA, pre, ctxbf,
                                             q_g, W_v, W_cov, padm, covl_part,
                                             flags, out, t);
  }

  // post (3 slots)
  k_fin<<<dim3(64),dim3(256),0,stream>>>(ctxP, S_part, P_exp, cov, covl_part, ctxA, out);
  mfma_gemm_ro<<<dim3(25,4),dim3(256),0,stream>>>(embU, h0bf, ctxA, wroT, RO, b_ro);
  k_post<<<dim3(4000),dim3(256),0,stream>>>(embU, h0bf, ctxA, W_pg, b_pg, RO, ro_g, out);
}

// Round 11
// 2758.841 us; speedup vs baseline: 1.1349x; 1.0073x over previous
//
#include <hip/hip_runtime.h>
#include <hip/hip_bf16.h>

// Decoder: T=50, B=64, S=400, D=E=H=A=512, POOL=2.
// R11: R10 with deadlock-safe block ordering (producers first):
//   blocks 0..63   = reducers (normalize ctxP(t-1)->bf16 ctxR, archive ctxA, flag_r)
//   blocks 64..71  = GRU (wait flag_r, stage ctxR+h, MFMA, q-partials, flag_g)
//   blocks 72..327 = energy (finalize t-1, preload streams, wait flag_g, compute)
// All dependency arrows point to earlier blockIdx -> no scheduler-capacity deadlock.

#define T_STEPS 50
#define BB 64
#define SS 400

// output offsets (floats)
#define O_GOUT 0
#define O_HID 819200
#define O_ATTN_LAST 851968
#define O_CTXF 877568
#define O_PG 910336
#define O_GATTN 913536
#define O_COVL 2193536
#define O_COVF 2196736

typedef __attribute__((ext_vector_type(4))) float f4;
typedef __attribute__((ext_vector_type(8))) short s8v;
typedef __attribute__((ext_vector_type(4))) unsigned u4;
typedef unsigned long long u64;

static __device__ __forceinline__ float bf2f(unsigned short u){
  unsigned v = ((unsigned)u) << 16; return __builtin_bit_cast(float, v);
}
static __device__ __forceinline__ unsigned short f2bf(float f){
  unsigned u = __builtin_bit_cast(unsigned, f);
  unsigned r = (u + 0x7FFFu + ((u >> 16) & 1u)) >> 16;
  return (unsigned short)r;
}
static __device__ __forceinline__ float sigmoidf_(float x){ return 1.f/(1.f+__expf(-x)); }
static __device__ __forceinline__ float tanhf_(float x){ float e=__expf(2.f*x); return 1.f - 2.f/(e+1.f); }
static __device__ __forceinline__ float ald32f(const float* p){
  unsigned u = __hip_atomic_load((const unsigned*)p, __ATOMIC_RELAXED, __HIP_MEMORY_SCOPE_AGENT);
  return __builtin_bit_cast(float, u);
}
static __device__ __forceinline__ void ast32f(float* p, float v){
  __hip_atomic_store((unsigned*)p, __builtin_bit_cast(unsigned, v),
                     __ATOMIC_RELAXED, __HIP_MEMORY_SCOPE_AGENT);
}
static __device__ __forceinline__ u64 ald64(const void* p){
  return __hip_atomic_load((const u64*)p, __ATOMIC_RELAXED, __HIP_MEMORY_SCOPE_AGENT);
}
static __device__ __forceinline__ void ast64(void* p, u64 v){
  __hip_atomic_store((u64*)p, v, __ATOMIC_RELAXED, __HIP_MEMORY_SCOPE_AGENT);
}

// ---------------- converts ----------------
__global__ void conv_ctx(const float* __restrict__ ctx, unsigned short* __restrict__ out){
  int o = blockIdx.x*256 + threadIdx.x;           // [S][B][E] -> [B][S][E] bf16
  if(o >= SS*BB*512) return;
  int e = o & 511; int b = (o>>9)&63; int s = o>>15;
  out[((b*SS+s)<<9) + e] = f2bf(ctx[o]);
}
__global__ void conv_emb(const int* __restrict__ y, const float* __restrict__ embW,
                         unsigned short* __restrict__ embU){
  int o = blockIdx.x*256+threadIdx.x; if(o>=T_STEPS*BB*512) return;
  int d = o & 511; int i = o>>9;
  embU[o] = f2bf(embW[(long)y[i]*512 + d]);
}
// fused small converts + init (+flag zeroing)
__global__ void conv_rest(const float* __restrict__ W_ih, const float* __restrict__ W_hh,
                          const float* __restrict__ W_pre, const float* __restrict__ W_ro,
                          const float* __restrict__ W_q,
                          const float* __restrict__ hidden, const float* __restrict__ init_att,
                          const float* __restrict__ gctx, const float* __restrict__ coverage,
                          unsigned short* __restrict__ wihbf, unsigned short* __restrict__ wpreT,
                          unsigned short* __restrict__ wroT, unsigned short* __restrict__ Wgru,
                          unsigned short* __restrict__ WqP,
                          float* __restrict__ hrow0, unsigned short* __restrict__ h0bf_init,
                          unsigned short* __restrict__ ctx0bf, float* __restrict__ gctxT,
                          float* __restrict__ cov, unsigned* __restrict__ flags){
  int o = blockIdx.x*256+threadIdx.x;
  if(o < 786432){
    int j = o>>9; int d = o&511;
    wihbf[o] = f2bf(W_ih[(long)j*1024 + d]);
  } else if(o < 1048576){
    int p = o - 786432;
    int a = p>>9; int e = p&511;
    wpreT[p] = f2bf(W_pre[(long)e*512 + a]);
  } else if(o < 2097152){
    int p = o - 1048576;
    int n = p>>11; int k = p&2047;
    wroT[p] = f2bf(W_ro[(long)k*512 + n]);
  } else if(o < 3670016){
    int p = o - 2097152;
    int rg = p >> 13; int rem = p & 8191;
    int ki = rem >> 9; int ln = (rem >> 3) & 63; int e = p & 7;
    int blk = rg/24; int r2 = rg%24; int w = r2/6; int r3 = r2%6; int g = r3>>1; int op = r3&1;
    int rl = ln & 15; int kk = ((ln>>4)<<3) + e;
    int d = blk*64 + w*16 + rl; int j = g*512 + d; int k = ki*32 + kk;
    float v = op ? W_hh[(long)j*512 + k] : W_ih[(long)j*1024 + 512 + k];
    Wgru[p] = f2bf(v);
  } else if(o < 3932160){
    int p = o - 3670016;
    int e = p&7; int ln=(p>>3)&63; int kf=(p>>9)&1; int nrg=(p>>10)&31; int blk=p>>15;
    int n = nrg*16 + (ln&15);
    int k = blk*64 + kf*32 + ((ln>>4)<<3) + e;
    WqP[p] = f2bf(W_q[(long)k*512 + n]);
  } else if(o < 4056192){
    int p = o - 3932160;
    if(p < 32768){ float v = hidden[p]; hrow0[p] = v; h0bf_init[p] = f2bf(v); }
    else if(p < 65536){ int q=p-32768; ctx0bf[q] = f2bf(init_att[q]); }
    else if(p < 98304){ int q=p-65536; int b=q>>9,e=q&511; gctxT[e*64+b]=gctx[q]; }
    else if(p < 123904){ int q=p-98304; cov[q]=coverage[q]; }
    else { int q=p-123904; if(q<128) flags[q]=0u; }
  }
}

// ---------------- MFMA GEMM (precompute) ----------------
template<int OUT_BF16>
__global__ __launch_bounds__(256) void mfma_gemm(
    const unsigned short* __restrict__ Abf, int lda,
    const unsigned short* __restrict__ Bbf, int ldb,
    void* __restrict__ Cp, int ldc, const float* __restrict__ bias, int K)
{
  __shared__ __align__(16) unsigned short Ash[128*40];
  __shared__ __align__(16) unsigned short Bsh[128*40];
  int m0 = blockIdx.x*128, n0 = blockIdx.y*128;
  int tid = threadIdx.x;
  int wid = tid>>6, lane = tid&63;
  int wm = wid>>1, wn = wid&1;
  int lr = lane&15, lg = lane>>4;
  f4 acc[4][4];
  #pragma unroll
  for(int i=0;i<4;i++)
    #pragma unroll
    for(int j=0;j<4;j++) acc[i][j]=(f4)0.f;

  for(int kt=0; kt<K; kt+=32){
    #pragma unroll
    for(int c=0;c<2;c++){
      int flat = tid*16 + c*8;
      int row = flat>>5, col = flat&31;
      const unsigned short* ga = Abf + (long)(m0+row)*lda + kt + col;
      *(uint4*)(&Ash[row*40+col]) = *(const uint4*)ga;
      const unsigned short* gb = Bbf + (long)(n0+row)*ldb + kt + col;
      *(uint4*)(&Bsh[row*40+col]) = *(const uint4*)gb;
    }
    __syncthreads();
    s8v av[4], bv[4];
    #pragma unroll
    for(int mi=0;mi<4;mi++) av[mi] = *(const s8v*)(&Ash[(wm*64+mi*16+lr)*40 + lg*8]);
    #pragma unroll
    for(int ni=0;ni<4;ni++) bv[ni] = *(const s8v*)(&Bsh[(wn*64+ni*16+lr)*40 + lg*8]);
    #pragma unroll
    for(int mi=0;mi<4;mi++)
      #pragma unroll
      for(int ni=0;ni<4;ni++)
        acc[mi][ni] = __builtin_amdgcn_mfma_f32_16x16x32_bf16(av[mi], bv[ni], acc[mi][ni], 0,0,0);
    __syncthreads();
  }
  #pragma unroll
  for(int mi=0;mi<4;mi++)
    #pragma unroll
    for(int ni=0;ni<4;ni++){
      int gc = n0 + wn*64 + ni*16 + lr;
      #pragma unroll
      for(int r=0;r<4;r++){
        int gr = m0 + wm*64 + mi*16 + lg*4 + r;
        float v = acc[mi][ni][r];
        if(bias) v += bias[gc];
        if(OUT_BF16) ((unsigned short*)Cp)[(long)gr*ldc + gc] = f2bf(v);
        else         ((float*)Cp)[(long)gr*ldc + gc] = v;
      }
    }
}

// ---------------- 3-source RO GEMM ----------------
__global__ __launch_bounds__(256) void mfma_gemm_ro(
    const unsigned short* __restrict__ embU, const unsigned short* __restrict__ h0bf,
    const unsigned short* __restrict__ ctxA, const unsigned short* __restrict__ wroT,
    float* __restrict__ RO, const float* __restrict__ bias)
{
  __shared__ __align__(16) unsigned short Ash[128*40];
  __shared__ __align__(16) unsigned short Bsh[128*40];
  int m0 = blockIdx.x*128, n0 = blockIdx.y*128;
  int tid = threadIdx.x;
  int wid = tid>>6, lane = tid&63;
  int wm = wid>>1, wn = wid&1;
  int lr = lane&15, lg = lane>>4;
  f4 acc[4][4];
  #pragma unroll
  for(int i=0;i<4;i++)
    #pragma unroll
    for(int j=0;j<4;j++) acc[i][j]=(f4)0.f;

  for(int kt=0; kt<1536; kt+=32){
    const unsigned short* src = (kt<512) ? embU : (kt<1024) ? h0bf : ctxA;
    int klocal = kt & 511;
    #pragma unroll
    for(int c=0;c<2;c++){
      int flat = tid*16 + c*8;
      int row = flat>>5, col = flat&31;
      *(uint4*)(&Ash[row*40+col]) = *(const uint4*)(src + (long)(m0+row)*512 + klocal + col);
      *(uint4*)(&Bsh[row*40+col]) = *(const uint4*)(wroT + (long)(n0+row)*2048 + kt + col);
    }
    __syncthreads();
    s8v av[4], bv[4];
    #pragma unroll
    for(int mi=0;mi<4;mi++) av[mi] = *(const s8v*)(&Ash[(wm*64+mi*16+lr)*40 + lg*8]);
    #pragma unroll
    for(int ni=0;ni<4;ni++) bv[ni] = *(const s8v*)(&Bsh[(wn*64+ni*16+lr)*40 + lg*8]);
    #pragma unroll
    for(int mi=0;mi<4;mi++)
      #pragma unroll
      for(int ni=0;ni<4;ni++)
        acc[mi][ni] = __builtin_amdgcn_mfma_f32_16x16x32_bf16(av[mi], bv[ni], acc[mi][ni], 0,0,0);
    __syncthreads();
  }
  #pragma unroll
  for(int mi=0;mi<4;mi++)
    #pragma unroll
    for(int ni=0;ni<4;ni++){
      int gc = n0 + wn*64 + ni*16 + lr;
      #pragma unroll
      for(int r=0;r<4;r++){
        int gr = m0 + wm*64 + mi*16 + lg*4 + r;
        RO[(long)gr*512 + gc] = acc[mi][ni][r] + bias[gc];
      }
    }
}

// ---------------- fused small fp32 GEMMs: q_g and ro_g ----------------
__global__ __launch_bounds__(256) void small2(
  const float* __restrict__ AT, const float* __restrict__ W_q, const float* __restrict__ W_ro,
  float* __restrict__ q_g, float* __restrict__ ro_g)
{
  int blk = blockIdx.x;
  int half = blk>>7; int nblk = blk&127;
  int tid = threadIdx.x;
  int b = tid&63; int nq = tid>>6;
  int n = __builtin_amdgcn_readfirstlane(nblk*4 + nq);
  const float* W = half ? W_ro : W_q;
  int koff = half ? 1536 : 512;
  float acc = 0.f;
  const float* wp = W + (long)koff*512 + n;
  #pragma unroll 8
  for(int k=0;k<512;k++){
    acc = fmaf(AT[k*64+b], wp[(long)k*512], acc);
  }
  (half ? ro_g : q_g)[b*512+n] = acc;
}

// ---------------- fused per-step kernel ----------------
// blocks 0..63: reducers; 64..71: GRU; 72..327: energy.
__global__ __launch_bounds__(512) void k_step(
  const unsigned short* __restrict__ ctx0bf, float* __restrict__ ctxP,
  float* __restrict__ S_part, float* __restrict__ P_exp,
  const unsigned short* __restrict__ hprevbf,
  const float* __restrict__ hrow_in, float* __restrict__ hrow_out,
  const unsigned short* __restrict__ Wp, const unsigned short* __restrict__ WqP,
  const float* __restrict__ gi_emb, const float* __restrict__ b_hh,
  unsigned short* __restrict__ h0bf_all, float* __restrict__ qpart,
  float* __restrict__ cov, unsigned short* __restrict__ ctxA,
  unsigned short* __restrict__ ctxR,
  const unsigned short* __restrict__ pre, const unsigned short* __restrict__ ctxbf,
  const float* __restrict__ q_g, const float* __restrict__ Wv,
  const float* __restrict__ Wcov, const float* __restrict__ padm,
  float* __restrict__ covl_part, unsigned* __restrict__ flags,
  float* __restrict__ outp, int t)
{
  __shared__ __align__(16) char smem[75008];
  const int blk = blockIdx.x;
  const int tid = threadIdx.x;
  const int w = tid>>6, lane = tid&63;
  const int lr = lane&15, lg = lane>>4;

  if(blk < 64){
    // ================= reducer block (producers first in dispatch order) =================
    if(t==0) return;
    int b = blk; int tb = t-1;
    if(tid < 128){
      const float* Sp = S_part + (tb&1)*256 + b*4;
      float inv = 1.f/(Sp[0]+Sp[1]+Sp[2]+Sp[3]);
      int e0 = tid*4;
      const float* cp = ctxP + (long)b*2048 + e0;
      f4 p0 = *(const f4*)cp;
      f4 p1 = *(const f4*)(cp+512);
      f4 p2 = *(const f4*)(cp+1024);
      f4 p3 = *(const f4*)(cp+1536);
      f4 s = (p0+p1+p2+p3)*inv;
      u64 v = (u64)f2bf(s.x) | ((u64)f2bf(s.y)<<16) | ((u64)f2bf(s.z)<<32) | ((u64)f2bf(s.w)<<48);
      ast64(ctxR + b*512 + e0, v);
      *(u64*)(ctxA + (long)(tb*64+b)*512 + e0) = v;
    }
    asm volatile("s_waitcnt vmcnt(0)" ::: "memory");
    __syncthreads();
    if(tid==0)
      __hip_atomic_fetch_add(flags+64+t, 1u, __ATOMIC_RELEASE, __HIP_MEMORY_SCOPE_AGENT);
    return;
  }

  if(blk < 72){
    // ================= GRU block (8 waves: dim-group x batch-half) =================
    int gblk = blk - 64;
    unsigned short* Ash = (unsigned short*)smem;            // 64KB
    unsigned short* HS  = (unsigned short*)(smem+65536);    // 9.2KB
    const int swz = (lr&7)<<4;
    const int dg = w&3, bh = w>>2;
    const int rgbase = gblk*24 + dg*6;

    if(t>0){
      if(tid==0){
        unsigned it=0;
        while(__hip_atomic_load(flags+64+t, __ATOMIC_RELAXED, __HIP_MEMORY_SCOPE_AGENT) < 64u){
          __builtin_amdgcn_s_sleep(2);
          if(++it > 20000000u) break;
        }
      }
      __syncthreads();
      asm volatile("" ::: "memory");
    }

    f4 acc2[6][2];
    #pragma unroll
    for(int u=0;u<6;u++)
      #pragma unroll
      for(int mm=0;mm<2;mm++) acc2[u][mm]=(f4)0.f;

    for(int kp=0; kp<2; kp++){
      for(int c = tid; c < 4096; c += 512){
        int op = c>>11; int row = (c>>5)&63; int kc = c&31;
        int e0 = kp*256 + kc*8;
        u4 v;
        if(op){
          v = *(const u4*)(hprevbf + row*512 + e0);
        } else if(t>0){
          u64 lo = ald64(ctxR + row*512 + e0);
          u64 hi = ald64(ctxR + row*512 + e0 + 4);
          v.x = (unsigned)lo; v.y = (unsigned)(lo>>32);
          v.z = (unsigned)hi; v.w = (unsigned)(hi>>32);
        } else {
          v = *(const u4*)(ctx0bf + row*512 + e0);
        }
        int dst = op*32768 + row*512 + ((kc*16) ^ ((row&7)<<4));
        *(u4*)((char*)Ash + dst) = v;
      }
      __syncthreads();
      {
        #pragma unroll 2
        for(int ktl=0; ktl<256; ktl+=32){
          s8v av[2][2];
          #pragma unroll
          for(int op=0;op<2;op++)
            #pragma unroll
            for(int mm=0;mm<2;mm++){
              int mi = bh*2+mm;
              av[op][mm] = *(const s8v*)((const char*)Ash + op*32768 + (mi*16+lr)*512 + ((ktl*2 + lg*16) ^ swz));
            }
          int ki = kp*8 + (ktl>>5);
          const unsigned short* wb = Wp + (long)rgbase*8192 + ki*512 + lane*8;
          #pragma unroll
          for(int u=0;u<6;u++){
            s8v bv = *(const s8v*)(wb + (long)u*8192);
            #pragma unroll
            for(int mm=0;mm<2;mm++)
              acc2[u][mm] = __builtin_amdgcn_mfma_f32_16x16x32_bf16(av[u&1][mm], bv, acc2[u][mm], 0,0,0);
          }
        }
      }
      __syncthreads();
    }

    {
      int d = gblk*64 + dg*16 + lr;
      float bhr = b_hh[d], bhz = b_hh[512+d], bhn = b_hh[1024+d];
      #pragma unroll
      for(int mm=0;mm<2;mm++){
        int mi = bh*2+mm;
        #pragma unroll
        for(int r=0;r<4;r++){
          int b = mi*16 + lg*4 + r;
          const float* ge = gi_emb + (long)(t*64+b)*1536;
          float g0 = __builtin_nontemporal_load(ge + d);
          float g1 = __builtin_nontemporal_load(ge + 512 + d);
          float g2 = __builtin_nontemporal_load(ge + 1024 + d);
          float rr = sigmoidf_(g0 + bhr + acc2[0][mm][r] + acc2[1][mm][r]);
          float zz = sigmoidf_(g1 + bhz + acc2[2][mm][r] + acc2[3][mm][r]);
          float nn = tanhf_(  g2       + acc2[4][mm][r] + rr*(acc2[5][mm][r] + bhn));
          float hp = hrow_in[b*512 + d];
          float hv = (1.f-zz)*nn + zz*hp;
          hrow_out[b*512+d] = hv;
          unsigned short hb = f2bf(hv);
          h0bf_all[(long)(t*64+b)*512 + d] = hb;
          HS[b*72 + dg*16 + lr] = hb;
          if(t==T_STEPS-1) outp[O_HID + b*512 + d] = hv;
        }
      }
    }
    __syncthreads();
    // q-partials: wave handles nrg = dg*8+i, batch-half bh
    {
      #pragma unroll
      for(int i=0;i<8;i++){
        f4 accq[2];
        accq[0]=(f4)0.f; accq[1]=(f4)0.f;
        #pragma unroll
        for(int kf=0;kf<2;kf++){
          s8v bv = *(const s8v*)(WqP + ((((long)gblk*32 + (dg*8+i))*2 + kf)*64 + lane)*8);
          #pragma unroll
          for(int mm=0;mm<2;mm++){
            int mi = bh*2+mm;
            s8v av = *(const s8v*)(HS + (mi*16+lr)*72 + kf*32 + lg*8);
            accq[mm] = __builtin_amdgcn_mfma_f32_16x16x32_bf16(av, bv, accq[mm], 0,0,0);
          }
        }
        int n = dg*128 + i*16 + lr;
        #pragma unroll
        for(int mm=0;mm<2;mm++)
          #pragma unroll
          for(int r=0;r<4;r++)
            ast32f(qpart + (long)gblk*32768 + (long)((bh*2+mm)*16+lg*4+r)*512 + n, accq[mm][r]);
      }
    }
    asm volatile("s_waitcnt vmcnt(0)" ::: "memory");
    __syncthreads();
    if(tid==0)
      __hip_atomic_fetch_add(flags+t, 1u, __ATOMIC_RELEASE, __HIP_MEMORY_SCOPE_AGENT);
    return;
  }

  // ================= energy block =================
  {
    int eb = blk-72; int b = eb>>2, cq = eb&3, c0 = cq*100;
    float* q_sh  = (float*)smem;
    float* wv_sh = (float*)(smem+2048);
    float* wc_sh = (float*)(smem+4096);
    float* covL  = (float*)(smem+6144);
    float* padL  = (float*)(smem+6560);
    float* red   = (float*)(smem+7392);
    float* red2  = (float*)(smem+9440);
    float* pb    = (float*)(smem+9472);   // [8][512]

    wv_sh[tid]=Wv[tid]; wc_sh[tid]=Wcov[tid];
    if(tid<100) padL[tid]=padm[b*400+c0+tid];
    // finalize step t-1 for this chunk (overlaps GRU+reduce)
    float clp = 0.f;
    if(t>0){
      const float* Sp = S_part + ((t-1)&1)*256 + b*4;
      float inv = 1.f/(Sp[0]+Sp[1]+Sp[2]+Sp[3]);
      if(tid<100){
        float p = P_exp[b*400+c0+tid]*inv;
        float co = cov[b*400+c0+tid];
        clp = fminf(p,co);
        float nc = co+p;
        cov[b*400+c0+tid]=nc;
        covL[tid]=nc;
        outp[O_GATTN + (long)(t-1)*25600 + b*400 + c0 + tid] = p;
      }
    } else {
      if(tid<100) covL[tid]=cov[b*400+c0+tid];
    }
    // preload this block's entire pre+ctx streams into registers (flies during GRU wait)
    const unsigned short* prow = pre   + (((long)(b*400+c0))<<9) + lane*8;
    const unsigned short* crow = ctxbf + (((long)(b*400+c0))<<9) + lane*8;
    u4 pr[13], cr[13];
    #pragma unroll
    for(int j=0;j<13;j++){
      int i = w + j*8;
      long ro = (long)((i<100)? i : 0) << 9;
      pr[j] = *(const u4*)(prow + ro);
      cr[j] = *(const u4*)(crow + ro);
    }
    red[tid]=clp; __syncthreads();
    for(int o=256;o;o>>=1){ if(tid<o) red[tid]+=red[tid+o]; __syncthreads(); }
    if(t>0 && tid==0) covl_part[(long)(t-1)*256 + b*4+cq] = red[0];
    // wait for q-partials
    if(tid==0){
      unsigned it=0;
      while(__hip_atomic_load(flags+t, __ATOMIC_RELAXED, __HIP_MEMORY_SCOPE_AGENT) < 8u){
        __builtin_amdgcn_s_sleep(8);
        if(++it > 20000000u) break;
      }
    }
    __syncthreads();
    asm volatile("" ::: "memory");
    // q reduce (agent loads)
    {
      float acc = q_g[b*512+tid];
      #pragma unroll
      for(int p=0;p<8;p++) acc += ald32f(qpart + ((long)p<<15) + b*512 + tid);
      q_sh[tid] = acc;
    }
    __syncthreads();
    // fused pass: energy -> exp -> ctx partial (registers already loaded)
    float wsum = 0.f;
    float acc8[8];
    #pragma unroll
    for(int j=0;j<8;j++) acc8[j]=0.f;
    #pragma unroll
    for(int j=0;j<13;j++){
      int i = w + j*8;
      if(i<100){
        u4 cur = pr[j];
        const unsigned* uu = (const unsigned*)&cur;
        float cv = covL[i];
        float part = 0.f;
        #pragma unroll
        for(int q4=0;q4<4;q4++){
          int a = lane*8 + q4*2;
          part += wv_sh[a]  * tanhf_(bf2f((unsigned short)(uu[q4]&0xffffu)) + q_sh[a]   + cv*wc_sh[a]);
          part += wv_sh[a+1]* tanhf_(bf2f((unsigned short)(uu[q4]>>16))    + q_sh[a+1] + cv*wc_sh[a+1]);
        }
        #pragma unroll
        for(int off=32;off;off>>=1) part += __shfl_xor(part, off, 64);
        float e = (padL[i]>0.5f) ? -1e18f : part;
        float p = __expf(e);
        if(lane==0) P_exp[b*400+c0+i] = p;
        wsum += p;
        u4 cc = cr[j];
        const unsigned* cu = (const unsigned*)&cc;
        acc8[0] = fmaf(p, bf2f((unsigned short)(cu[0]&0xffffu)), acc8[0]);
        acc8[1] = fmaf(p, bf2f((unsigned short)(cu[0]>>16)),     acc8[1]);
        acc8[2] = fmaf(p, bf2f((unsigned short)(cu[1]&0xffffu)), acc8[2]);
        acc8[3] = fmaf(p, bf2f((unsigned short)(cu[1]>>16)),     acc8[3]);
        acc8[4] = fmaf(p, bf2f((unsigned short)(cu[2]&0xffffu)), acc8[4]);
        acc8[5] = fmaf(p, bf2f((unsigned short)(cu[2]>>16)),     acc8[5]);
        acc8[6] = fmaf(p, bf2f((unsigned short)(cu[3]&0xffffu)), acc8[6]);
        acc8[7] = fmaf(p, bf2f((unsigned short)(cu[3]>>16)),     acc8[7]);
      }
    }
    if(lane==0) red2[w]=wsum;
    __syncthreads();
    if(tid==0)
      S_part[(t&1)*256 + b*4+cq] = red2[0]+red2[1]+red2[2]+red2[3]+red2[4]+red2[5]+red2[6]+red2[7];
    #pragma unroll
    for(int j=0;j<8;j++) pb[w*512 + lane*8+j] = acc8[j];
    __syncthreads();
    {
      float v = pb[tid]+pb[512+tid]+pb[1024+tid]+pb[1536+tid]
               +pb[2048+tid]+pb[2560+tid]+pb[3072+tid]+pb[3584+tid];
      ctxP[((long)b*4+cq)*512 + tid] = v;
    }
  }
}

// ---------------- k_fin: finalize step 49 + all covl ----------------
__global__ __launch_bounds__(256) void k_fin(
  const float* __restrict__ ctxP, const float* __restrict__ S_part,
  const float* __restrict__ P_exp, const float* __restrict__ cov,
  const float* __restrict__ covl_part,
  unsigned short* __restrict__ ctxA, float* __restrict__ outp)
{
  __shared__ float red[256];
  int b = blockIdx.x; int tid = threadIdx.x;
  const int tb = T_STEPS-1;
  const float* Sp = S_part + 256 + b*4;   // parity of t=49 is 1
  float S = Sp[0]+Sp[1]+Sp[2]+Sp[3];
  float inv = 1.f/S;
  float clp;
  {
    float p = P_exp[b*400+tid]*inv;
    float co = cov[b*400+tid];
    clp = fminf(p, co);
    float nc = co+p;
    outp[O_GATTN + (long)tb*25600 + b*400 + tid] = p;
    outp[O_ATTN_LAST + b*400 + tid] = p;
    outp[O_COVF + b*400 + tid] = nc;
  }
  if(tid<144){
    int i = 256+tid;
    float p = P_exp[b*400+i]*inv;
    float co = cov[b*400+i];
    clp += fminf(p, co);
    float nc = co+p;
    outp[O_GATTN + (long)tb*25600 + b*400 + i] = p;
    outp[O_ATTN_LAST + b*400 + i] = p;
    outp[O_COVF + b*400 + i] = nc;
  }
  red[tid]=clp; __syncthreads();
  for(int o=128;o;o>>=1){ if(tid<o) red[tid]+=red[tid+o]; __syncthreads(); }
  if(tid==0) outp[O_COVL + tb*64 + b] = red[0];
  if(tid<49){
    const float* cp = covl_part + (long)tid*256 + b*4;
    outp[O_COVL + tid*64 + b] = cp[0]+cp[1]+cp[2]+cp[3];
  }
  for(int c=tid;c<512;c+=256){
    float v = (ctxP[(long)b*2048+c]+ctxP[(long)b*2048+512+c]
              +ctxP[(long)b*2048+1024+c]+ctxP[(long)b*2048+1536+c])*inv;
    outp[O_CTXF + b*512 + c] = v;
    ctxA[(long)(tb*64+b)*512 + c] = f2bf(v);
  }
}

// ---------------- fused post: pgen + maxout ----------------
__global__ __launch_bounds__(256) void k_post(
  const unsigned short* __restrict__ embU, const unsigned short* __restrict__ h0bf,
  const unsigned short* __restrict__ ctxA, const float* __restrict__ Wpg,
  const float* __restrict__ bpg, const float* __restrict__ RO,
  const float* __restrict__ ro_g, float* __restrict__ outp)
{
  int blk = blockIdx.x;
  if(blk < 800){
    int wid = threadIdx.x>>6, lane=threadIdx.x&63;
    int m = blk*4 + wid;
    float acc=0.f;
    #pragma unroll
    for(int i=0;i<8;i++){
      int k = i*64+lane;
      acc = fmaf(bf2f(ctxA[(long)m*512+k]), Wpg[k], acc);
      acc = fmaf(bf2f(h0bf[(long)m*512+k]), Wpg[512+k], acc);
      acc = fmaf(bf2f(embU[(long)m*512+k]), Wpg[1024+k], acc);
    }
    #pragma unroll
    for(int off=32; off; off>>=1) acc += __shfl_xor(acc, off, 64);
    if(lane==0) outp[O_PG + m] = sigmoidf_(acc + bpg[0]);
  } else {
    int o = (blk-800)*256 + threadIdx.x;
    int h = o & 255; int m = o>>8; int b = m & 63;
    float v0 = RO[(long)m*512 + 2*h]   + ro_g[b*512 + 2*h];
    float v1 = RO[(long)m*512 + 2*h+1] + ro_g[b*512 + 2*h+1];
    outp[O_GOUT + o] = fmaxf(v0,v1);
  }
}

extern "C" void kernel_launch(void* const* d_in, const int* in_sizes, int n_in,
                              void* d_out, int out_size, void* d_ws, size_t ws_size,
                              hipStream_t stream)
{
  (void)in_sizes; (void)n_in; (void)out_size; (void)ws_size;
  const int*   y       = (const int*)d_in[0];
  const float* hidden  = (const float*)d_in[1];
  const float* context = (const float*)d_in[2];
  const float* padm    = (const float*)d_in[3];
  const float* init_att= (const float*)d_in[4];
  const float* coverage= (const float*)d_in[5];
  const float* gctx    = (const float*)d_in[6];
  const float* embW    = (const float*)d_in[7];
  const float* W_ih    = (const float*)d_in[8];
  const float* W_hh    = (const float*)d_in[9];
  const float* b_ih    = (const float*)d_in[10];
  const float* b_hh    = (const float*)d_in[11];
  const float* W_pre   = (const float*)d_in[12];
  const float* b_pre   = (const float*)d_in[13];
  const float* W_q     = (const float*)d_in[14];
  const float* W_v     = (const float*)d_in[15];
  const float* W_cov   = (const float*)d_in[16];
  const float* W_pg    = (const float*)d_in[17];
  const float* b_pg    = (const float*)d_in[18];
  const float* W_ro    = (const float*)d_in[19];
  const float* b_ro    = (const float*)d_in[20];
  float* out = (float*)d_out;

  char* wsb = (char*)d_ws;
  size_t off = 0;
  auto alloc = [&](size_t bytes)->char*{ char* p = wsb+off; off += (bytes+255)&~255UL; return p; };
  unsigned short* pre    = (unsigned short*)alloc(25600UL*512*2);
  unsigned short* ctxbf  = (unsigned short*)alloc(13107200UL*2);
  unsigned short* embU   = (unsigned short*)alloc(3200UL*512*2);
  unsigned short* wihbf  = (unsigned short*)alloc(1536UL*512*2);
  unsigned short* wpreT  = (unsigned short*)alloc(512UL*512*2);
  unsigned short* wroT   = (unsigned short*)alloc(512UL*2048*2);
  unsigned short* Wgru   = (unsigned short*)alloc(192UL*8192*2);
  unsigned short* WqP    = (unsigned short*)alloc(262144UL*2);
  float* gi_emb = (float*)alloc(3200UL*1536*4);
  float* RO     = (float*)alloc(3200UL*512*4);
  float* q_g    = (float*)alloc(64UL*512*4);
  float* ro_g   = (float*)alloc(64UL*512*4);
  float* hrow0  = (float*)alloc(64UL*512*4);
  float* hrow1  = (float*)alloc(64UL*512*4);
  float* gctxT  = (float*)alloc(512UL*64*4);
  unsigned short* h0bf = (unsigned short*)alloc(3200UL*512*2);
  unsigned short* h0bf_init = (unsigned short*)alloc(64UL*512*2);
  unsigned short* ctx0bf    = (unsigned short*)alloc(64UL*512*2);
  unsigned short* ctxA = (unsigned short*)alloc(3200UL*512*2);
  unsigned short* ctxR = (unsigned short*)alloc(64UL*512*2);
  float* ctxP   = (float*)alloc(64UL*4*512*4);
  float* P_exp  = (float*)alloc(64UL*400*4);
  float* S_part = (float*)alloc(2UL*256*4);
  float* qpart  = (float*)alloc(8UL*64*512*4);
  float* cov    = (float*)alloc(64UL*400*4);
  float* covl_part = (float*)alloc(50UL*256*4);
  unsigned* flags = (unsigned*)alloc(128UL*4);

  // converts + init (3 slots)
  conv_ctx <<<dim3(51200),dim3(256),0,stream>>>(context, ctxbf);
  conv_emb <<<dim3(6400), dim3(256),0,stream>>>(y, embW, embU);
  conv_rest<<<dim3(15845),dim3(256),0,stream>>>(W_ih, W_hh, W_pre, W_ro, W_q,
                                                hidden, init_att, gctx, coverage,
                                                wihbf, wpreT, wroT, Wgru, WqP,
                                                hrow0, h0bf_init, ctx0bf, gctxT, cov, flags);

  // precompute GEMMs (3 slots)
  mfma_gemm<1><<<dim3(200,4),dim3(256),0,stream>>>(ctxbf,512, wpreT,512,  pre,   512, b_pre, 512);
  mfma_gemm<0><<<dim3(25,12),dim3(256),0,stream>>>(embU, 512, wihbf,512,  gi_emb,1536, b_ih, 512);
  small2<<<dim3(256),dim3(256),0,stream>>>(gctxT, W_q, W_ro, q_g, ro_g);

  // scan: 1 kernel/step
  for(int t=0; t<T_STEPS; t++){
    float* hin  = (t&1) ? hrow1 : hrow0;
    float* hout = (t&1) ? hrow0 : hrow1;
    const unsigned short* hprevbf = t ? (h0bf + (long)(t-1)*32768) : h0bf_init;
    k_step<<<dim3(328),dim3(512),0,stream>>>(ctx0bf, ctxP, S_part, P_exp, hprevbf,
                                             hin, hout, Wgru, WqP, gi_emb, b_hh,
                                             h0bf, qpart, cov, ctxA, ctxR, pre, ctxbf,
                                             q_g, W_v, W_cov, padm, covl_part,
                                             flags, out, t);
  }

  // post (3 slots)
  k_fin<<<dim3(64),dim3(256),0,stream>>>(ctxP, S_part, P_exp, cov, covl_part, ctxA, out);
  mfma_gemm_ro<<<dim3(25,4),dim3(256),0,stream>>>(embU, h0bf, ctxA, wroT, RO, b_ro);
  k_post<<<dim3(4000),dim3(256),0,stream>>>(embU, h0bf, ctxA, W_pg, b_pg, RO, ro_g, out);
}